// Round 1
// baseline (492.566 us; speedup 1.0000x reference)
//
#include <hip/hip_runtime.h>
#include <hip/hip_bf16.h>

#define N_NODES 50000
#define E0      800000
#define E_TOT   850000   // +N self loops

// ---------------------------------------------------------------- CSR build
__global__ __launch_bounds__(256) void count_deg(const int* __restrict__ ei, int* __restrict__ deg) {
    int e = blockIdx.x * 256 + threadIdx.x;
    if (e >= E_TOT) return;
    int dst = (e < E0) ? ei[E0 + e] : (e - E0);
    atomicAdd(&deg[dst], 1);
}

// single-block exclusive scan; reads deg from `cursor`, writes exclusive prefix to
// both `offs` (persistent) and `cursor` (scatter cursors). n must be %4==0.
__global__ __launch_bounds__(1024) void scan_kernel(int* __restrict__ cursor, int* __restrict__ offs, int n) {
    __shared__ int wsum[16];
    __shared__ int carry_sh;
    int t = threadIdx.x, lane = t & 63, wid = t >> 6;
    if (t == 0) carry_sh = 0;
    __syncthreads();
    for (int base = 0; base < n; base += 4096) {
        int idx = base + t * 4;
        int4 v = make_int4(0, 0, 0, 0);
        if (idx < n) v = *reinterpret_cast<const int4*>(cursor + idx);
        int tsum = v.x + v.y + v.z + v.w;
        int sc = tsum;
        #pragma unroll
        for (int s = 1; s < 64; s <<= 1) {
            int up = __shfl_up(sc, s);
            if (lane >= s) sc += up;
        }
        if (lane == 63) wsum[wid] = sc;
        __syncthreads();
        int carry = carry_sh;
        int woff = 0;
        for (int w = 0; w < wid; ++w) woff += wsum[w];
        int b0 = carry + woff + (sc - tsum);
        if (idx < n) {
            int4 o;
            o.x = b0;
            o.y = b0 + v.x;
            o.z = b0 + v.x + v.y;
            o.w = b0 + v.x + v.y + v.z;
            *reinterpret_cast<int4*>(offs + idx)   = o;
            *reinterpret_cast<int4*>(cursor + idx) = o;
        }
        __syncthreads();
        if (t == 0) {
            int tt = 0;
            #pragma unroll
            for (int w = 0; w < 16; ++w) tt += wsum[w];
            carry_sh = carry + tt;
        }
        __syncthreads();
    }
    if (t == 0) offs[n] = carry_sh;
}

__global__ __launch_bounds__(256) void scatter_edges(const int* __restrict__ ei, int* __restrict__ cursor,
                                                     int* __restrict__ ssrc) {
    int e = blockIdx.x * 256 + threadIdx.x;
    if (e >= E_TOT) return;
    int src, dst;
    if (e < E0) { src = ei[e]; dst = ei[E0 + e]; }
    else        { src = dst = e - E0; }
    int pos = atomicAdd(&cursor[dst], 1);
    ssrc[pos] = src;
}

// ---------------------------------------------------------------- GEMM (fp32, LDS-staged)
// 256 threads: 32 rows x M cols per block; thread -> row=t>>3, cols (t&7)+8*j
template <int K, int M>
__global__ __launch_bounds__(256) void gemm_kernel(const float* __restrict__ X, const float* __restrict__ W,
                                                   float* __restrict__ Hout, int nRows) {
    constexpr int ROWS = 32;
    constexpr int JN = M / 8;
    __shared__ float Ws[K][M];
    __shared__ float Xs[ROWS][K + 1];
    int t = threadIdx.x;
    for (int i = t; i < K * M; i += 256) Ws[i / M][i % M] = W[i];
    int r0 = blockIdx.x * ROWS;
    for (int i = t; i < ROWS * K; i += 256) {
        int r = i / K, k = i % K;
        int gr = r0 + r;
        Xs[r][k] = (gr < nRows) ? X[(size_t)gr * K + k] : 0.f;
    }
    __syncthreads();
    int r = t >> 3;
    int cl = t & 7;
    float acc[JN];
    #pragma unroll
    for (int j = 0; j < JN; ++j) acc[j] = 0.f;
    #pragma unroll 4
    for (int k = 0; k < K; ++k) {
        float xv = Xs[r][k];
        #pragma unroll
        for (int j = 0; j < JN; ++j) acc[j] += xv * Ws[k][cl + 8 * j];
    }
    int gr = r0 + r;
    if (gr < nRows) {
        #pragma unroll
        for (int j = 0; j < JN; ++j) Hout[(size_t)gr * M + cl + 8 * j] = acc[j];
    }
}

// ---------------------------------------------------------------- attention dot products
// layer1: H=2 heads, C=64. wave per node, lane = channel.
__global__ __launch_bounds__(256) void att_dots2h(const float* __restrict__ Hm, const float* __restrict__ asrc,
                                                  const float* __restrict__ adst, float* __restrict__ as,
                                                  float* __restrict__ ad, int n) {
    int node = blockIdx.x * 4 + (threadIdx.x >> 6);
    if (node >= n) return;
    int lane = threadIdx.x & 63;
    const float* hrow = Hm + (size_t)node * 128;
    float h0 = hrow[lane];
    float h1 = hrow[64 + lane];
    float ps0 = h0 * asrc[lane],      pd0 = h0 * adst[lane];
    float ps1 = h1 * asrc[64 + lane], pd1 = h1 * adst[64 + lane];
    #pragma unroll
    for (int s = 32; s > 0; s >>= 1) {
        ps0 += __shfl_xor(ps0, s);
        pd0 += __shfl_xor(pd0, s);
        ps1 += __shfl_xor(ps1, s);
        pd1 += __shfl_xor(pd1, s);
    }
    if (lane == 0) {
        as[node * 2] = ps0; ad[node * 2] = pd0;
        as[node * 2 + 1] = ps1; ad[node * 2 + 1] = pd1;
    }
}

// layer2: H=1, C=40
__global__ __launch_bounds__(256) void att_dots40(const float* __restrict__ Hm, const float* __restrict__ asrc,
                                                  const float* __restrict__ adst, float* __restrict__ as,
                                                  float* __restrict__ ad, int n) {
    int node = blockIdx.x * 4 + (threadIdx.x >> 6);
    if (node >= n) return;
    int lane = threadIdx.x & 63;
    float h = (lane < 40) ? Hm[(size_t)node * 40 + lane] : 0.f;
    float ps = (lane < 40) ? h * asrc[lane] : 0.f;
    float pd = (lane < 40) ? h * adst[lane] : 0.f;
    #pragma unroll
    for (int s = 32; s > 0; s >>= 1) {
        ps += __shfl_xor(ps, s);
        pd += __shfl_xor(pd, s);
    }
    if (lane == 0) { as[node] = ps; ad[node] = pd; }
}

__device__ __forceinline__ float lrelu(float x) { return x > 0.f ? x : 0.2f * x; }

// ---------------------------------------------------------------- aggregation layer1 (+bias+ELU)
__global__ __launch_bounds__(256) void aggregate1(const float* __restrict__ Hm, const float* __restrict__ as,
                                                  const float* __restrict__ ad, const int* __restrict__ offs,
                                                  const int* __restrict__ ssrc, const float* __restrict__ bias,
                                                  float* __restrict__ Xout, int n) {
    int node = blockIdx.x * 4 + (threadIdx.x >> 6);
    if (node >= n) return;
    int lane = threadIdx.x & 63;
    int beg = offs[node], end = offs[node + 1];
    float ad0 = ad[node * 2], ad1 = ad[node * 2 + 1];
    float m0 = -3.4e38f, m1 = -3.4e38f;
    for (int i = beg + lane; i < end; i += 64) {
        int s = ssrc[i];
        m0 = fmaxf(m0, lrelu(as[s * 2]     + ad0));
        m1 = fmaxf(m1, lrelu(as[s * 2 + 1] + ad1));
    }
    #pragma unroll
    for (int s = 32; s > 0; s >>= 1) {
        m0 = fmaxf(m0, __shfl_xor(m0, s));
        m1 = fmaxf(m1, __shfl_xor(m1, s));
    }
    float acc0 = 0.f, acc1 = 0.f, den0 = 0.f, den1 = 0.f;
    for (int i = beg; i < end; ++i) {
        int s = ssrc[i];
        float w0 = __expf(lrelu(as[s * 2]     + ad0) - m0);
        float w1 = __expf(lrelu(as[s * 2 + 1] + ad1) - m1);
        den0 += w0; den1 += w1;
        acc0 += w0 * Hm[(size_t)s * 128 + lane];
        acc1 += w1 * Hm[(size_t)s * 128 + 64 + lane];
    }
    float o0 = acc0 / (den0 + 1e-16f) + bias[lane];
    float o1 = acc1 / (den1 + 1e-16f) + bias[64 + lane];
    o0 = o0 > 0.f ? o0 : (__expf(o0) - 1.f);   // ELU
    o1 = o1 > 0.f ? o1 : (__expf(o1) - 1.f);
    Xout[(size_t)node * 128 + lane]      = o0;
    Xout[(size_t)node * 128 + 64 + lane] = o1;
}

// ---------------------------------------------------------------- aggregation layer2 (+bias) -> out
__global__ __launch_bounds__(256) void aggregate2(const float* __restrict__ Hm, const float* __restrict__ as,
                                                  const float* __restrict__ ad, const int* __restrict__ offs,
                                                  const int* __restrict__ ssrc, const float* __restrict__ bias,
                                                  float* __restrict__ out, int n) {
    int node = blockIdx.x * 4 + (threadIdx.x >> 6);
    if (node >= n) return;
    int lane = threadIdx.x & 63;
    int beg = offs[node], end = offs[node + 1];
    float adv = ad[node];
    float m = -3.4e38f;
    for (int i = beg + lane; i < end; i += 64) {
        int s = ssrc[i];
        m = fmaxf(m, lrelu(as[s] + adv));
    }
    #pragma unroll
    for (int s = 32; s > 0; s >>= 1) m = fmaxf(m, __shfl_xor(m, s));
    float acc = 0.f, den = 0.f;
    for (int i = beg; i < end; ++i) {
        int s = ssrc[i];
        float w = __expf(lrelu(as[s] + adv) - m);
        den += w;
        if (lane < 40) acc += w * Hm[(size_t)s * 40 + lane];
    }
    if (lane < 40) out[(size_t)node * 40 + lane] = acc / (den + 1e-16f) + bias[lane];
}

// ---------------------------------------------------------------- launch
extern "C" void kernel_launch(void* const* d_in, const int* in_sizes, int n_in,
                              void* d_out, int out_size, void* d_ws, size_t ws_size,
                              hipStream_t stream) {
    (void)in_sizes; (void)n_in; (void)out_size; (void)ws_size;
    const float* x    = (const float*)d_in[0];
    const int*   ei   = (const int*)d_in[1];
    const float* W1   = (const float*)d_in[2];
    const float* as1w = (const float*)d_in[3];
    const float* ad1w = (const float*)d_in[4];
    const float* b1   = (const float*)d_in[5];
    const float* W2   = (const float*)d_in[6];
    const float* as2w = (const float*)d_in[7];
    const float* ad2w = (const float*)d_in[8];
    const float* b2   = (const float*)d_in[9];
    float* out = (float*)d_out;

    float* ws = (float*)d_ws;
    float* h1   = ws; ws += (size_t)N_NODES * 128;
    float* x2   = ws; ws += (size_t)N_NODES * 128;
    float* a_s1 = ws; ws += N_NODES * 2;
    float* a_d1 = ws; ws += N_NODES * 2;
    float* a_s2 = ws; ws += N_NODES;
    float* a_d2 = ws; ws += N_NODES;
    float* h2   = ws; ws += (size_t)N_NODES * 40;
    int* offs   = (int*)ws;
    int* cursor = offs + 50004;           // 50001 used, padded for 16B alignment
    int* ssrc   = cursor + N_NODES;

    hipMemsetAsync(cursor, 0, N_NODES * sizeof(int), stream);
    count_deg<<<(E_TOT + 255) / 256, 256, 0, stream>>>(ei, cursor);
    scan_kernel<<<1, 1024, 0, stream>>>(cursor, offs, N_NODES);
    scatter_edges<<<(E_TOT + 255) / 256, 256, 0, stream>>>(ei, cursor, ssrc);

    gemm_kernel<128, 128><<<(N_NODES + 31) / 32, 256, 0, stream>>>(x, W1, h1, N_NODES);
    att_dots2h<<<(N_NODES + 3) / 4, 256, 0, stream>>>(h1, as1w, ad1w, a_s1, a_d1, N_NODES);
    aggregate1<<<(N_NODES + 3) / 4, 256, 0, stream>>>(h1, a_s1, a_d1, offs, ssrc, b1, x2, N_NODES);
    gemm_kernel<128, 40><<<(N_NODES + 31) / 32, 256, 0, stream>>>(x2, W2, h2, N_NODES);
    att_dots40<<<(N_NODES + 3) / 4, 256, 0, stream>>>(h2, as2w, ad2w, a_s2, a_d2, N_NODES);
    aggregate2<<<(N_NODES + 3) / 4, 256, 0, stream>>>(h2, a_s2, a_d2, offs, ssrc, b2, out, N_NODES);
}

// Round 2
// 304.878 us; speedup vs baseline: 1.6156x; 1.6156x over previous
//
#include <hip/hip_runtime.h>
#include <hip/hip_bf16.h>

#define N_NODES 50000
#define E0      800000
#define E_TOT   850000   // +N self loops

// ---------------------------------------------------------------- CSR build
__global__ __launch_bounds__(256) void count_deg(const int* __restrict__ ei, int* __restrict__ deg) {
    int e = blockIdx.x * 256 + threadIdx.x;
    if (e >= E_TOT) return;
    int dst = (e < E0) ? ei[E0 + e] : (e - E0);
    atomicAdd(&deg[dst], 1);
}

__global__ __launch_bounds__(1024) void scan_kernel(int* __restrict__ cursor, int* __restrict__ offs, int n) {
    __shared__ int wsum[16];
    __shared__ int carry_sh;
    int t = threadIdx.x, lane = t & 63, wid = t >> 6;
    if (t == 0) carry_sh = 0;
    __syncthreads();
    for (int base = 0; base < n; base += 4096) {
        int idx = base + t * 4;
        int4 v = make_int4(0, 0, 0, 0);
        if (idx < n) v = *reinterpret_cast<const int4*>(cursor + idx);
        int tsum = v.x + v.y + v.z + v.w;
        int sc = tsum;
        #pragma unroll
        for (int s = 1; s < 64; s <<= 1) {
            int up = __shfl_up(sc, s);
            if (lane >= s) sc += up;
        }
        if (lane == 63) wsum[wid] = sc;
        __syncthreads();
        int carry = carry_sh;
        int woff = 0;
        for (int w = 0; w < wid; ++w) woff += wsum[w];
        int b0 = carry + woff + (sc - tsum);
        if (idx < n) {
            int4 o;
            o.x = b0;
            o.y = b0 + v.x;
            o.z = b0 + v.x + v.y;
            o.w = b0 + v.x + v.y + v.z;
            *reinterpret_cast<int4*>(offs + idx)   = o;
            *reinterpret_cast<int4*>(cursor + idx) = o;
        }
        __syncthreads();
        if (t == 0) {
            int tt = 0;
            #pragma unroll
            for (int w = 0; w < 16; ++w) tt += wsum[w];
            carry_sh = carry + tt;
        }
        __syncthreads();
    }
    if (t == 0) offs[n] = carry_sh;
}

__global__ __launch_bounds__(256) void scatter_edges(const int* __restrict__ ei, int* __restrict__ cursor,
                                                     int* __restrict__ ssrc) {
    int e = blockIdx.x * 256 + threadIdx.x;
    if (e >= E_TOT) return;
    int src, dst;
    if (e < E0) { src = ei[e]; dst = ei[E0 + e]; }
    else        { src = dst = e - E0; }
    int pos = atomicAdd(&cursor[dst], 1);
    ssrc[pos] = src;
}

__device__ __forceinline__ float lrelu(float x) { return x > 0.f ? x : 0.2f * x; }

// ---------------------------------------------------------------- GEMM1 fused (X@W1 + att dots), K=128, M=128
// 64 rows x 128 cols per block; thread: 4 rows (trow=t>>4) x 8 cols (tcol=t&15)
__global__ __launch_bounds__(256) void gemm1_fused(const float* __restrict__ X, const float* __restrict__ W,
                                                   const float* __restrict__ asw, const float* __restrict__ adw,
                                                   float* __restrict__ h1, float* __restrict__ a_s,
                                                   float* __restrict__ a_d, int nRows) {
    __shared__ float Ws[32][128];
    __shared__ float Xst[32][68];   // transposed X tile [k][row], pad 68 (272B = 17*16, 16B-aligned rows)
    int t = threadIdx.x;
    int tcol = t & 15, trow = t >> 4;
    int r0 = blockIdx.x * 64;
    float acc[4][8];
    #pragma unroll
    for (int r = 0; r < 4; ++r)
        #pragma unroll
        for (int j = 0; j < 8; ++j) acc[r][j] = 0.f;
    float asv[8], adv[8];
    #pragma unroll
    for (int j = 0; j < 8; ++j) { asv[j] = asw[tcol * 8 + j]; adv[j] = adw[tcol * 8 + j]; }

    for (int kc = 0; kc < 4; ++kc) {
        int k0 = kc * 32;
        __syncthreads();
        // stage W chunk [32][128]
        #pragma unroll
        for (int i = 0; i < 4; ++i) {
            int idx = t * 4 + i * 1024;           // 0..4095
            float4 wv = *reinterpret_cast<const float4*>(&W[(size_t)(k0 + (idx >> 7)) * 128 + (idx & 127)]);
            *reinterpret_cast<float4*>(&Ws[idx >> 7][idx & 127]) = wv;
        }
        // stage X chunk transposed
        #pragma unroll
        for (int i = 0; i < 2; ++i) {
            int li = t + i * 256;                  // 0..511
            int r = li >> 3;
            int kk = (li & 7) * 4;
            int gr = r0 + r;
            float4 xv = make_float4(0.f, 0.f, 0.f, 0.f);
            if (gr < nRows) xv = *reinterpret_cast<const float4*>(&X[(size_t)gr * 128 + k0 + kk]);
            Xst[kk][r] = xv.x; Xst[kk + 1][r] = xv.y; Xst[kk + 2][r] = xv.z; Xst[kk + 3][r] = xv.w;
        }
        __syncthreads();
        #pragma unroll 8
        for (int k = 0; k < 32; ++k) {
            float4 xv = *reinterpret_cast<const float4*>(&Xst[k][trow * 4]);
            float4 w0 = *reinterpret_cast<const float4*>(&Ws[k][tcol * 8]);
            float4 w1 = *reinterpret_cast<const float4*>(&Ws[k][tcol * 8 + 4]);
            float xr[4] = {xv.x, xv.y, xv.z, xv.w};
            float wc[8] = {w0.x, w0.y, w0.z, w0.w, w1.x, w1.y, w1.z, w1.w};
            #pragma unroll
            for (int r = 0; r < 4; ++r)
                #pragma unroll
                for (int j = 0; j < 8; ++j) acc[r][j] += xr[r] * wc[j];
        }
    }
    // epilogue: att partial dots + reduce over 8 lanes (per head)
    float ps[4], pd[4];
    #pragma unroll
    for (int r = 0; r < 4; ++r) {
        float s = 0.f, d = 0.f;
        #pragma unroll
        for (int j = 0; j < 8; ++j) { s += acc[r][j] * asv[j]; d += acc[r][j] * adv[j]; }
        ps[r] = s; pd[r] = d;
    }
    #pragma unroll
    for (int sh = 1; sh < 8; sh <<= 1) {
        #pragma unroll
        for (int r = 0; r < 4; ++r) { ps[r] += __shfl_xor(ps[r], sh); pd[r] += __shfl_xor(pd[r], sh); }
    }
    int head = tcol >> 3;
    #pragma unroll
    for (int r = 0; r < 4; ++r) {
        int gr = r0 + trow * 4 + r;
        if (gr < nRows) {
            if ((tcol & 7) == 0) { a_s[gr * 2 + head] = ps[r]; a_d[gr * 2 + head] = pd[r]; }
            float4 o0 = make_float4(acc[r][0], acc[r][1], acc[r][2], acc[r][3]);
            float4 o1 = make_float4(acc[r][4], acc[r][5], acc[r][6], acc[r][7]);
            *reinterpret_cast<float4*>(&h1[(size_t)gr * 128 + tcol * 8])     = o0;
            *reinterpret_cast<float4*>(&h1[(size_t)gr * 128 + tcol * 8 + 4]) = o1;
        }
    }
}

// ---------------------------------------------------------------- GEMM2 fused (X2@W2 + att dots), K=128, M=40
// 64 rows per block; thread: 1 row (trow=t>>2) x 10 cols strided (col = tcol + 4j, tcol=t&3)
__global__ __launch_bounds__(256) void gemm2_fused(const float* __restrict__ X, const float* __restrict__ W,
                                                   const float* __restrict__ asw, const float* __restrict__ adw,
                                                   float* __restrict__ h2, float* __restrict__ a_s,
                                                   float* __restrict__ a_d, int nRows) {
    __shared__ float Ws[32][40];
    __shared__ float Xst[32][68];
    int t = threadIdx.x;
    int tcol = t & 3, trow = t >> 2;
    int r0 = blockIdx.x * 64;
    float acc[10];
    #pragma unroll
    for (int j = 0; j < 10; ++j) acc[j] = 0.f;
    float asv[10], adv[10];
    #pragma unroll
    for (int j = 0; j < 10; ++j) { asv[j] = asw[tcol + 4 * j]; adv[j] = adw[tcol + 4 * j]; }

    for (int kc = 0; kc < 4; ++kc) {
        int k0 = kc * 32;
        __syncthreads();
        for (int i = t; i < 32 * 40; i += 256) Ws[i / 40][i % 40] = W[(size_t)(k0 + i / 40) * 40 + (i % 40)];
        #pragma unroll
        for (int i = 0; i < 2; ++i) {
            int li = t + i * 256;
            int r = li >> 3;
            int kk = (li & 7) * 4;
            int gr = r0 + r;
            float4 xv = make_float4(0.f, 0.f, 0.f, 0.f);
            if (gr < nRows) xv = *reinterpret_cast<const float4*>(&X[(size_t)gr * 128 + k0 + kk]);
            Xst[kk][r] = xv.x; Xst[kk + 1][r] = xv.y; Xst[kk + 2][r] = xv.z; Xst[kk + 3][r] = xv.w;
        }
        __syncthreads();
        #pragma unroll 8
        for (int k = 0; k < 32; ++k) {
            float xv = Xst[k][trow];
            #pragma unroll
            for (int j = 0; j < 10; ++j) acc[j] += xv * Ws[k][tcol + 4 * j];
        }
    }
    float ps = 0.f, pd = 0.f;
    #pragma unroll
    for (int j = 0; j < 10; ++j) { ps += acc[j] * asv[j]; pd += acc[j] * adv[j]; }
    ps += __shfl_xor(ps, 1); pd += __shfl_xor(pd, 1);
    ps += __shfl_xor(ps, 2); pd += __shfl_xor(pd, 2);
    int gr = r0 + trow;
    if (gr < nRows) {
        if (tcol == 0) { a_s[gr] = ps; a_d[gr] = pd; }
        #pragma unroll
        for (int j = 0; j < 10; ++j) h2[(size_t)gr * 40 + tcol + 4 * j] = acc[j];
    }
}

// ---------------------------------------------------------------- aggregation layer1 (+bias+ELU)
// 2 waves per node (one per head); block = 4 waves = 2 nodes
__global__ __launch_bounds__(256) void aggregate1(const float* __restrict__ Hm, const float* __restrict__ as,
                                                  const float* __restrict__ ad, const int* __restrict__ offs,
                                                  const int* __restrict__ ssrc, const float* __restrict__ bias,
                                                  float* __restrict__ Xout, int n) {
    __shared__ int   sbuf[4][64];
    __shared__ float wbuf[4][64];
    int t = threadIdx.x, lane = t & 63, wid = t >> 6;
    int node = blockIdx.x * 2 + (wid >> 1);
    int head = wid & 1;
    if (node >= n) return;
    int beg = offs[node], end = offs[node + 1];
    float adh = ad[node * 2 + head];
    float den = 0.f, acc = 0.f;
    for (int i0 = beg; i0 < end; i0 += 64) {
        int cnt = min(64, end - i0);
        int s = 0; float w = 0.f;
        if (lane < cnt) {
            s = ssrc[i0 + lane];
            w = __expf(lrelu(as[s * 2 + head] + adh));
        }
        sbuf[wid][lane] = s;
        wbuf[wid][lane] = w;
        den += w;
        #pragma unroll 4
        for (int j = 0; j < cnt; ++j) {
            acc += wbuf[wid][j] * Hm[(size_t)sbuf[wid][j] * 128 + head * 64 + lane];
        }
    }
    #pragma unroll
    for (int sh = 32; sh > 0; sh >>= 1) den += __shfl_xor(den, sh);
    float o = acc / (den + 1e-16f) + bias[head * 64 + lane];
    o = o > 0.f ? o : (__expf(o) - 1.f);   // ELU
    Xout[(size_t)node * 128 + head * 64 + lane] = o;
}

// ---------------------------------------------------------------- aggregation layer2 (+bias) -> out
__global__ __launch_bounds__(256) void aggregate2(const float* __restrict__ Hm, const float* __restrict__ as,
                                                  const float* __restrict__ ad, const int* __restrict__ offs,
                                                  const int* __restrict__ ssrc, const float* __restrict__ bias,
                                                  float* __restrict__ out, int n) {
    __shared__ int   sbuf[4][64];
    __shared__ float wbuf[4][64];
    int t = threadIdx.x, lane = t & 63, wid = t >> 6;
    int node = blockIdx.x * 4 + wid;
    if (node >= n) return;
    int beg = offs[node], end = offs[node + 1];
    float adv = ad[node];
    float den = 0.f, acc = 0.f;
    for (int i0 = beg; i0 < end; i0 += 64) {
        int cnt = min(64, end - i0);
        int s = 0; float w = 0.f;
        if (lane < cnt) {
            s = ssrc[i0 + lane];
            w = __expf(lrelu(as[s] + adv));
        }
        sbuf[wid][lane] = s;
        wbuf[wid][lane] = w;
        den += w;
        #pragma unroll 4
        for (int j = 0; j < cnt; ++j) {
            if (lane < 40) acc += wbuf[wid][j] * Hm[(size_t)sbuf[wid][j] * 40 + lane];
        }
    }
    #pragma unroll
    for (int sh = 32; sh > 0; sh >>= 1) den += __shfl_xor(den, sh);
    if (lane < 40) out[(size_t)node * 40 + lane] = acc / (den + 1e-16f) + bias[lane];
}

// ---------------------------------------------------------------- launch
extern "C" void kernel_launch(void* const* d_in, const int* in_sizes, int n_in,
                              void* d_out, int out_size, void* d_ws, size_t ws_size,
                              hipStream_t stream) {
    (void)in_sizes; (void)n_in; (void)out_size; (void)ws_size;
    const float* x    = (const float*)d_in[0];
    const int*   ei   = (const int*)d_in[1];
    const float* W1   = (const float*)d_in[2];
    const float* as1w = (const float*)d_in[3];
    const float* ad1w = (const float*)d_in[4];
    const float* b1   = (const float*)d_in[5];
    const float* W2   = (const float*)d_in[6];
    const float* as2w = (const float*)d_in[7];
    const float* ad2w = (const float*)d_in[8];
    const float* b2   = (const float*)d_in[9];
    float* out = (float*)d_out;

    float* ws = (float*)d_ws;
    float* h1   = ws; ws += (size_t)N_NODES * 128;
    float* x2   = ws; ws += (size_t)N_NODES * 128;
    float* a_s1 = ws; ws += N_NODES * 2;
    float* a_d1 = ws; ws += N_NODES * 2;
    float* a_s2 = ws; ws += N_NODES;
    float* a_d2 = ws; ws += N_NODES;
    float* h2   = ws; ws += (size_t)N_NODES * 40;
    int* offs   = (int*)ws;
    int* cursor = offs + 50004;           // 50001 used, padded for 16B alignment
    int* ssrc   = cursor + N_NODES;

    hipMemsetAsync(cursor, 0, N_NODES * sizeof(int), stream);
    count_deg<<<(E_TOT + 255) / 256, 256, 0, stream>>>(ei, cursor);
    scan_kernel<<<1, 1024, 0, stream>>>(cursor, offs, N_NODES);
    scatter_edges<<<(E_TOT + 255) / 256, 256, 0, stream>>>(ei, cursor, ssrc);

    gemm1_fused<<<(N_NODES + 63) / 64, 256, 0, stream>>>(x, W1, as1w, ad1w, h1, a_s1, a_d1, N_NODES);
    aggregate1<<<(N_NODES + 1) / 2, 256, 0, stream>>>(h1, a_s1, a_d1, offs, ssrc, b1, x2, N_NODES);
    gemm2_fused<<<(N_NODES + 63) / 64, 256, 0, stream>>>(x2, W2, as2w, ad2w, h2, a_s2, a_d2, N_NODES);
    aggregate2<<<(N_NODES + 3) / 4, 256, 0, stream>>>(h2, a_s2, a_d2, offs, ssrc, b2, out, N_NODES);
}

// Round 3
// 268.352 us; speedup vs baseline: 1.8355x; 1.1361x over previous
//
#include <hip/hip_runtime.h>
#include <hip/hip_bf16.h>

#define N_NODES 50000
#define E0      800000
#define E_TOT   850000   // +N self loops

// ---------------------------------------------------------------- CSR build
__global__ __launch_bounds__(256) void count_deg(const int* __restrict__ ei, int* __restrict__ deg) {
    int e = blockIdx.x * 256 + threadIdx.x;
    if (e >= E_TOT) return;
    int dst = (e < E0) ? ei[E0 + e] : (e - E0);
    atomicAdd(&deg[dst], 1);
}

__global__ __launch_bounds__(1024) void scan_kernel(int* __restrict__ cursor, int* __restrict__ offs, int n) {
    __shared__ int wsum[16];
    __shared__ int carry_sh;
    int t = threadIdx.x, lane = t & 63, wid = t >> 6;
    if (t == 0) carry_sh = 0;
    __syncthreads();
    for (int base = 0; base < n; base += 4096) {
        int idx = base + t * 4;
        int4 v = make_int4(0, 0, 0, 0);
        if (idx < n) v = *reinterpret_cast<const int4*>(cursor + idx);
        int tsum = v.x + v.y + v.z + v.w;
        int sc = tsum;
        #pragma unroll
        for (int s = 1; s < 64; s <<= 1) {
            int up = __shfl_up(sc, s);
            if (lane >= s) sc += up;
        }
        if (lane == 63) wsum[wid] = sc;
        __syncthreads();
        int carry = carry_sh;
        int woff = 0;
        for (int w = 0; w < wid; ++w) woff += wsum[w];
        int b0 = carry + woff + (sc - tsum);
        if (idx < n) {
            int4 o;
            o.x = b0;
            o.y = b0 + v.x;
            o.z = b0 + v.x + v.y;
            o.w = b0 + v.x + v.y + v.z;
            *reinterpret_cast<int4*>(offs + idx)   = o;
            *reinterpret_cast<int4*>(cursor + idx) = o;
        }
        __syncthreads();
        if (t == 0) {
            int tt = 0;
            #pragma unroll
            for (int w = 0; w < 16; ++w) tt += wsum[w];
            carry_sh = carry + tt;
        }
        __syncthreads();
    }
    if (t == 0) offs[n] = carry_sh;
}

__global__ __launch_bounds__(256) void scatter_edges(const int* __restrict__ ei, int* __restrict__ cursor,
                                                     int* __restrict__ ssrc) {
    int e = blockIdx.x * 256 + threadIdx.x;
    if (e >= E_TOT) return;
    int src, dst;
    if (e < E0) { src = ei[e]; dst = ei[E0 + e]; }
    else        { src = dst = e - E0; }
    int pos = atomicAdd(&cursor[dst], 1);
    ssrc[pos] = src;
}

__device__ __forceinline__ float lrelu(float x) { return x > 0.f ? x : 0.2f * x; }

// ---------------------------------------------------------------- GEMM1 fused (X@W1 + att dots), K=128, M=128
__global__ __launch_bounds__(256) void gemm1_fused(const float* __restrict__ X, const float* __restrict__ W,
                                                   const float* __restrict__ asw, const float* __restrict__ adw,
                                                   float* __restrict__ h1, float* __restrict__ a_s,
                                                   float* __restrict__ a_d, int nRows) {
    __shared__ float Ws[32][128];
    __shared__ float Xst[32][68];
    int t = threadIdx.x;
    int tcol = t & 15, trow = t >> 4;
    int r0 = blockIdx.x * 64;
    float acc[4][8];
    #pragma unroll
    for (int r = 0; r < 4; ++r)
        #pragma unroll
        for (int j = 0; j < 8; ++j) acc[r][j] = 0.f;
    float asv[8], adv[8];
    #pragma unroll
    for (int j = 0; j < 8; ++j) { asv[j] = asw[tcol * 8 + j]; adv[j] = adw[tcol * 8 + j]; }

    for (int kc = 0; kc < 4; ++kc) {
        int k0 = kc * 32;
        __syncthreads();
        #pragma unroll
        for (int i = 0; i < 4; ++i) {
            int idx = t * 4 + i * 1024;
            float4 wv = *reinterpret_cast<const float4*>(&W[(size_t)(k0 + (idx >> 7)) * 128 + (idx & 127)]);
            *reinterpret_cast<float4*>(&Ws[idx >> 7][idx & 127]) = wv;
        }
        #pragma unroll
        for (int i = 0; i < 2; ++i) {
            int li = t + i * 256;
            int r = li >> 3;
            int kk = (li & 7) * 4;
            int gr = r0 + r;
            float4 xv = make_float4(0.f, 0.f, 0.f, 0.f);
            if (gr < nRows) xv = *reinterpret_cast<const float4*>(&X[(size_t)gr * 128 + k0 + kk]);
            Xst[kk][r] = xv.x; Xst[kk + 1][r] = xv.y; Xst[kk + 2][r] = xv.z; Xst[kk + 3][r] = xv.w;
        }
        __syncthreads();
        #pragma unroll 8
        for (int k = 0; k < 32; ++k) {
            float4 xv = *reinterpret_cast<const float4*>(&Xst[k][trow * 4]);
            float4 w0 = *reinterpret_cast<const float4*>(&Ws[k][tcol * 8]);
            float4 w1 = *reinterpret_cast<const float4*>(&Ws[k][tcol * 8 + 4]);
            float xr[4] = {xv.x, xv.y, xv.z, xv.w};
            float wc[8] = {w0.x, w0.y, w0.z, w0.w, w1.x, w1.y, w1.z, w1.w};
            #pragma unroll
            for (int r = 0; r < 4; ++r)
                #pragma unroll
                for (int j = 0; j < 8; ++j) acc[r][j] += xr[r] * wc[j];
        }
    }
    float ps[4], pd[4];
    #pragma unroll
    for (int r = 0; r < 4; ++r) {
        float s = 0.f, d = 0.f;
        #pragma unroll
        for (int j = 0; j < 8; ++j) { s += acc[r][j] * asv[j]; d += acc[r][j] * adv[j]; }
        ps[r] = s; pd[r] = d;
    }
    #pragma unroll
    for (int sh = 1; sh < 8; sh <<= 1) {
        #pragma unroll
        for (int r = 0; r < 4; ++r) { ps[r] += __shfl_xor(ps[r], sh); pd[r] += __shfl_xor(pd[r], sh); }
    }
    int head = tcol >> 3;
    #pragma unroll
    for (int r = 0; r < 4; ++r) {
        int gr = r0 + trow * 4 + r;
        if (gr < nRows) {
            if ((tcol & 7) == 0) { a_s[gr * 2 + head] = ps[r]; a_d[gr * 2 + head] = pd[r]; }
            float4 o0 = make_float4(acc[r][0], acc[r][1], acc[r][2], acc[r][3]);
            float4 o1 = make_float4(acc[r][4], acc[r][5], acc[r][6], acc[r][7]);
            *reinterpret_cast<float4*>(&h1[(size_t)gr * 128 + tcol * 8])     = o0;
            *reinterpret_cast<float4*>(&h1[(size_t)gr * 128 + tcol * 8 + 4]) = o1;
        }
    }
}

// ---------------------------------------------------------------- GEMM2 fused (X2@W2 + att dots), K=128, M=40
__global__ __launch_bounds__(256) void gemm2_fused(const float* __restrict__ X, const float* __restrict__ W,
                                                   const float* __restrict__ asw, const float* __restrict__ adw,
                                                   float* __restrict__ h2, float* __restrict__ a_s,
                                                   float* __restrict__ a_d, int nRows) {
    __shared__ float Ws[32][40];
    __shared__ float Xst[32][68];
    int t = threadIdx.x;
    int tcol = t & 3, trow = t >> 2;
    int r0 = blockIdx.x * 64;
    float acc[10];
    #pragma unroll
    for (int j = 0; j < 10; ++j) acc[j] = 0.f;
    float asv[10], adv[10];
    #pragma unroll
    for (int j = 0; j < 10; ++j) { asv[j] = asw[tcol + 4 * j]; adv[j] = adw[tcol + 4 * j]; }

    for (int kc = 0; kc < 4; ++kc) {
        int k0 = kc * 32;
        __syncthreads();
        for (int i = t; i < 32 * 40; i += 256) Ws[i / 40][i % 40] = W[(size_t)(k0 + i / 40) * 40 + (i % 40)];
        #pragma unroll
        for (int i = 0; i < 2; ++i) {
            int li = t + i * 256;
            int r = li >> 3;
            int kk = (li & 7) * 4;
            int gr = r0 + r;
            float4 xv = make_float4(0.f, 0.f, 0.f, 0.f);
            if (gr < nRows) xv = *reinterpret_cast<const float4*>(&X[(size_t)gr * 128 + k0 + kk]);
            Xst[kk][r] = xv.x; Xst[kk + 1][r] = xv.y; Xst[kk + 2][r] = xv.z; Xst[kk + 3][r] = xv.w;
        }
        __syncthreads();
        #pragma unroll 8
        for (int k = 0; k < 32; ++k) {
            float xv = Xst[k][trow];
            #pragma unroll
            for (int j = 0; j < 10; ++j) acc[j] += xv * Ws[k][tcol + 4 * j];
        }
    }
    float ps = 0.f, pd = 0.f;
    #pragma unroll
    for (int j = 0; j < 10; ++j) { ps += acc[j] * asv[j]; pd += acc[j] * adv[j]; }
    ps += __shfl_xor(ps, 1); pd += __shfl_xor(pd, 1);
    ps += __shfl_xor(ps, 2); pd += __shfl_xor(pd, 2);
    int gr = r0 + trow;
    if (gr < nRows) {
        if (tcol == 0) { a_s[gr] = ps; a_d[gr] = pd; }
        #pragma unroll
        for (int j = 0; j < 10; ++j) h2[(size_t)gr * 40 + tcol + 4 * j] = acc[j];
    }
}

// ---------------------------------------------------------------- aggregation layer1 (+bias+ELU)
// one wave per node, both heads; lane covers ch {2l, 2l+1}; float2 gathers, 4 accs
__global__ __launch_bounds__(256) void aggregate1(const float* __restrict__ Hm, const float* __restrict__ as,
                                                  const float* __restrict__ ad, const int* __restrict__ offs,
                                                  const int* __restrict__ ssrc, const float* __restrict__ bias,
                                                  float* __restrict__ Xout, int n) {
    __shared__ int   sbuf[4][64];
    __shared__ float wbuf[4][2][64];
    int t = threadIdx.x, lane = t & 63, wid = t >> 6;
    int node = blockIdx.x * 4 + wid;
    if (node >= n) return;
    int beg = offs[node], end = offs[node + 1];
    float ad0 = ad[node * 2], ad1 = ad[node * 2 + 1];
    int head = lane >> 5;     // ch 2l,2l+1 -> head = (2l>=64)
    float den0 = 0.f, den1 = 0.f;
    float2 acc0 = make_float2(0.f, 0.f), acc1 = acc0, acc2 = acc0, acc3 = acc0;
    for (int i0 = beg; i0 < end; i0 += 64) {
        int cnt = min(64, end - i0);
        int s = 0; float w0 = 0.f, w1 = 0.f;
        if (lane < cnt) {
            s = ssrc[i0 + lane];
            w0 = __expf(lrelu(as[s * 2]     + ad0));
            w1 = __expf(lrelu(as[s * 2 + 1] + ad1));
        }
        sbuf[wid][lane] = s;
        wbuf[wid][0][lane] = w0;
        wbuf[wid][1][lane] = w1;
        den0 += w0; den1 += w1;
        int j = 0;
        for (; j + 4 <= cnt; j += 4) {
            int s0 = sbuf[wid][j],     s1 = sbuf[wid][j + 1];
            int s2 = sbuf[wid][j + 2], s3 = sbuf[wid][j + 3];
            float wa = wbuf[wid][head][j],     wb = wbuf[wid][head][j + 1];
            float wc = wbuf[wid][head][j + 2], wd = wbuf[wid][head][j + 3];
            float2 ha = *reinterpret_cast<const float2*>(&Hm[(size_t)s0 * 128 + lane * 2]);
            float2 hb = *reinterpret_cast<const float2*>(&Hm[(size_t)s1 * 128 + lane * 2]);
            float2 hc = *reinterpret_cast<const float2*>(&Hm[(size_t)s2 * 128 + lane * 2]);
            float2 hd = *reinterpret_cast<const float2*>(&Hm[(size_t)s3 * 128 + lane * 2]);
            acc0.x += wa * ha.x; acc0.y += wa * ha.y;
            acc1.x += wb * hb.x; acc1.y += wb * hb.y;
            acc2.x += wc * hc.x; acc2.y += wc * hc.y;
            acc3.x += wd * hd.x; acc3.y += wd * hd.y;
        }
        for (; j < cnt; ++j) {
            int s0 = sbuf[wid][j];
            float wa = wbuf[wid][head][j];
            float2 ha = *reinterpret_cast<const float2*>(&Hm[(size_t)s0 * 128 + lane * 2]);
            acc0.x += wa * ha.x; acc0.y += wa * ha.y;
        }
    }
    acc0.x += acc1.x + acc2.x + acc3.x;
    acc0.y += acc1.y + acc2.y + acc3.y;
    #pragma unroll
    for (int sh = 32; sh > 0; sh >>= 1) { den0 += __shfl_xor(den0, sh); den1 += __shfl_xor(den1, sh); }
    float den = (head ? den1 : den0) + 1e-16f;
    float2 bv = *reinterpret_cast<const float2*>(&bias[lane * 2]);
    float ox = acc0.x / den + bv.x;
    float oy = acc0.y / den + bv.y;
    ox = ox > 0.f ? ox : (__expf(ox) - 1.f);
    oy = oy > 0.f ? oy : (__expf(oy) - 1.f);
    *reinterpret_cast<float2*>(&Xout[(size_t)node * 128 + lane * 2]) = make_float2(ox, oy);
}

// ---------------------------------------------------------------- aggregation layer2 (+bias) -> out
// one wave per node; 3 edge-groups x 20 lanes x float2 (2ch); accs merged via shfl
__global__ __launch_bounds__(256) void aggregate2(const float* __restrict__ Hm, const float* __restrict__ as,
                                                  const float* __restrict__ ad, const int* __restrict__ offs,
                                                  const int* __restrict__ ssrc, const float* __restrict__ bias,
                                                  float* __restrict__ out, int n) {
    __shared__ int   sbuf[4][66];
    __shared__ float wbuf[4][66];
    int t = threadIdx.x, lane = t & 63, wid = t >> 6;
    int node = blockIdx.x * 4 + wid;
    if (node >= n) return;
    int beg = offs[node], end = offs[node + 1];
    float adv = ad[node];
    int g = lane / 20;          // 0,1,2 ; lanes 60-63 -> clamp
    int c2 = lane % 20;
    if (g == 3) g = 2;          // lanes 60-63 mirror lanes 40-43 (harmless dup)
    float den = 0.f;
    float2 acc = make_float2(0.f, 0.f);
    float2 acc_b = make_float2(0.f, 0.f);
    if (lane < 2) { sbuf[wid][64 + lane] = 0; wbuf[wid][64 + lane] = 0.f; }
    for (int i0 = beg; i0 < end; i0 += 64) {
        int cnt = min(64, end - i0);
        int s = 0; float w = 0.f;
        if (lane < cnt) {
            s = ssrc[i0 + lane];
            w = __expf(lrelu(as[s] + adv));
        }
        sbuf[wid][lane] = s;
        wbuf[wid][lane] = w;
        if (lane >= cnt) { sbuf[wid][lane] = 0; wbuf[wid][lane] = 0.f; }
        den += w;
        for (int j = 0; j < cnt; j += 6) {
            int ja = j + g, jb = j + 3 + g;
            int   sa = sbuf[wid][ja], sb2 = sbuf[wid][jb];
            float wa = wbuf[wid][ja], wb2 = wbuf[wid][jb];
            float2 ha = *reinterpret_cast<const float2*>(&Hm[(size_t)sa * 40 + c2 * 2]);
            float2 hb = *reinterpret_cast<const float2*>(&Hm[(size_t)sb2 * 40 + c2 * 2]);
            acc.x   += wa * ha.x;  acc.y   += wa * ha.y;
            acc_b.x += wb2 * hb.x; acc_b.y += wb2 * hb.y;
        }
    }
    acc.x += acc_b.x; acc.y += acc_b.y;
    #pragma unroll
    for (int sh = 32; sh > 0; sh >>= 1) den += __shfl_xor(den, sh);
    // merge the 3 groups: lane l (<20) += lane l+20, l+40
    float ax1 = __shfl(acc.x, lane + 20), ay1 = __shfl(acc.y, lane + 20);
    float ax2 = __shfl(acc.x, lane + 40), ay2 = __shfl(acc.y, lane + 40);
    if (lane < 20) {
        float ox = (acc.x + ax1 + ax2) / (den + 1e-16f) + bias[c2 * 2];
        float oy = (acc.y + ay1 + ay2) / (den + 1e-16f) + bias[c2 * 2 + 1];
        *reinterpret_cast<float2*>(&out[(size_t)node * 40 + c2 * 2]) = make_float2(ox, oy);
    }
}

// ---------------------------------------------------------------- launch
extern "C" void kernel_launch(void* const* d_in, const int* in_sizes, int n_in,
                              void* d_out, int out_size, void* d_ws, size_t ws_size,
                              hipStream_t stream) {
    (void)in_sizes; (void)n_in; (void)out_size; (void)ws_size;
    const float* x    = (const float*)d_in[0];
    const int*   ei   = (const int*)d_in[1];
    const float* W1   = (const float*)d_in[2];
    const float* as1w = (const float*)d_in[3];
    const float* ad1w = (const float*)d_in[4];
    const float* b1   = (const float*)d_in[5];
    const float* W2   = (const float*)d_in[6];
    const float* as2w = (const float*)d_in[7];
    const float* ad2w = (const float*)d_in[8];
    const float* b2   = (const float*)d_in[9];
    float* out = (float*)d_out;

    float* ws = (float*)d_ws;
    float* h1   = ws; ws += (size_t)N_NODES * 128;
    float* x2   = ws; ws += (size_t)N_NODES * 128;
    float* a_s1 = ws; ws += N_NODES * 2;
    float* a_d1 = ws; ws += N_NODES * 2;
    float* a_s2 = ws; ws += N_NODES;
    float* a_d2 = ws; ws += N_NODES;
    float* h2   = ws; ws += (size_t)N_NODES * 40;
    int* offs   = (int*)ws;
    int* cursor = offs + 50004;
    int* ssrc   = cursor + N_NODES;

    hipMemsetAsync(cursor, 0, N_NODES * sizeof(int), stream);
    count_deg<<<(E_TOT + 255) / 256, 256, 0, stream>>>(ei, cursor);
    scan_kernel<<<1, 1024, 0, stream>>>(cursor, offs, N_NODES);
    scatter_edges<<<(E_TOT + 255) / 256, 256, 0, stream>>>(ei, cursor, ssrc);

    gemm1_fused<<<(N_NODES + 63) / 64, 256, 0, stream>>>(x, W1, as1w, ad1w, h1, a_s1, a_d1, N_NODES);
    aggregate1<<<(N_NODES + 3) / 4, 256, 0, stream>>>(h1, a_s1, a_d1, offs, ssrc, b1, x2, N_NODES);
    gemm2_fused<<<(N_NODES + 63) / 64, 256, 0, stream>>>(x2, W2, as2w, ad2w, h2, a_s2, a_d2, N_NODES);
    aggregate2<<<(N_NODES + 3) / 4, 256, 0, stream>>>(h2, a_s2, a_d2, offs, ssrc, b2, out, N_NODES);
}

// Round 4
// 199.717 us; speedup vs baseline: 2.4663x; 1.3437x over previous
//
#include <hip/hip_runtime.h>
#include <hip/hip_bf16.h>

#define N_NODES 50000
#define E0      800000
#define E_TOT   850000   // +N self loops

__device__ __forceinline__ float lrelu(float x) { return x > 0.f ? x : 0.2f * x; }

__device__ __forceinline__ unsigned short f2bf(float f) {   // RNE fp32->bf16
    unsigned int u = __float_as_uint(f);
    u += 0x7fffu + ((u >> 16) & 1u);
    return (unsigned short)(u >> 16);
}
__device__ __forceinline__ float lo_bf(unsigned int p) { return __uint_as_float(p << 16); }
__device__ __forceinline__ float hi_bf(unsigned int p) { return __uint_as_float(p & 0xffff0000u); }

// ---------------------------------------------------------------- CSR build
__global__ __launch_bounds__(256) void count_deg(const int* __restrict__ ei, int* __restrict__ deg,
                                                 int* __restrict__ rank) {
    int e = blockIdx.x * 256 + threadIdx.x;
    if (e >= E_TOT) return;
    int dst = (e < E0) ? ei[E0 + e] : (e - E0);
    rank[e] = atomicAdd(&deg[dst], 1);
}

__global__ __launch_bounds__(1024) void scan_kernel(const int* __restrict__ deg, int* __restrict__ offs, int n) {
    __shared__ int wsum[16];
    __shared__ int carry_sh;
    int t = threadIdx.x, lane = t & 63, wid = t >> 6;
    if (t == 0) carry_sh = 0;
    __syncthreads();
    for (int base = 0; base < n; base += 4096) {
        int idx = base + t * 4;
        int4 v = make_int4(0, 0, 0, 0);
        if (idx < n) v = *reinterpret_cast<const int4*>(deg + idx);
        int tsum = v.x + v.y + v.z + v.w;
        int sc = tsum;
        #pragma unroll
        for (int s = 1; s < 64; s <<= 1) {
            int up = __shfl_up(sc, s);
            if (lane >= s) sc += up;
        }
        if (lane == 63) wsum[wid] = sc;
        __syncthreads();
        int carry = carry_sh;
        int woff = 0;
        for (int w = 0; w < wid; ++w) woff += wsum[w];
        int b0 = carry + woff + (sc - tsum);
        if (idx < n) {
            int4 o;
            o.x = b0;
            o.y = b0 + v.x;
            o.z = b0 + v.x + v.y;
            o.w = b0 + v.x + v.y + v.z;
            *reinterpret_cast<int4*>(offs + idx) = o;
        }
        __syncthreads();
        if (t == 0) {
            int tt = 0;
            #pragma unroll
            for (int w = 0; w < 16; ++w) tt += wsum[w];
            carry_sh = carry + tt;
        }
        __syncthreads();
    }
    if (t == 0) offs[n] = carry_sh;
}

__global__ __launch_bounds__(256) void scatter_edges(const int* __restrict__ ei, const int* __restrict__ offs,
                                                     const int* __restrict__ rank, int* __restrict__ ssrc) {
    int e = blockIdx.x * 256 + threadIdx.x;
    if (e >= E_TOT) return;
    int src, dst;
    if (e < E0) { src = ei[e]; dst = ei[E0 + e]; }
    else        { src = dst = e - E0; }
    ssrc[offs[dst] + rank[e]] = src;
}

// ---------------------------------------------------------------- GEMM1 fused (X@W1 + att dots), bf16 h1 out
__global__ __launch_bounds__(256) void gemm1_fused(const float* __restrict__ X, const float* __restrict__ W,
                                                   const float* __restrict__ asw, const float* __restrict__ adw,
                                                   unsigned short* __restrict__ h1b, float* __restrict__ a_s,
                                                   float* __restrict__ a_d, int nRows) {
    __shared__ float Ws[32][128];
    __shared__ float Xst[32][68];
    int t = threadIdx.x;
    int tcol = t & 15, trow = t >> 4;
    int r0 = blockIdx.x * 64;
    float acc[4][8];
    #pragma unroll
    for (int r = 0; r < 4; ++r)
        #pragma unroll
        for (int j = 0; j < 8; ++j) acc[r][j] = 0.f;
    float asv[8], adv[8];
    #pragma unroll
    for (int j = 0; j < 8; ++j) { asv[j] = asw[tcol * 8 + j]; adv[j] = adw[tcol * 8 + j]; }

    for (int kc = 0; kc < 4; ++kc) {
        int k0 = kc * 32;
        __syncthreads();
        #pragma unroll
        for (int i = 0; i < 4; ++i) {
            int idx = t * 4 + i * 1024;
            float4 wv = *reinterpret_cast<const float4*>(&W[(size_t)k0 * 128 + idx]);
            *reinterpret_cast<float4*>(&Ws[idx >> 7][idx & 127]) = wv;
        }
        #pragma unroll
        for (int i = 0; i < 2; ++i) {
            int li = t + i * 256;
            int r = li >> 3;
            int kk = (li & 7) * 4;
            int gr = r0 + r;
            float4 xv = make_float4(0.f, 0.f, 0.f, 0.f);
            if (gr < nRows) xv = *reinterpret_cast<const float4*>(&X[(size_t)gr * 128 + k0 + kk]);
            Xst[kk][r] = xv.x; Xst[kk + 1][r] = xv.y; Xst[kk + 2][r] = xv.z; Xst[kk + 3][r] = xv.w;
        }
        __syncthreads();
        #pragma unroll 8
        for (int k = 0; k < 32; ++k) {
            float4 xv = *reinterpret_cast<const float4*>(&Xst[k][trow * 4]);
            float4 w0 = *reinterpret_cast<const float4*>(&Ws[k][tcol * 8]);
            float4 w1 = *reinterpret_cast<const float4*>(&Ws[k][tcol * 8 + 4]);
            float xr[4] = {xv.x, xv.y, xv.z, xv.w};
            float wc[8] = {w0.x, w0.y, w0.z, w0.w, w1.x, w1.y, w1.z, w1.w};
            #pragma unroll
            for (int r = 0; r < 4; ++r)
                #pragma unroll
                for (int j = 0; j < 8; ++j) acc[r][j] += xr[r] * wc[j];
        }
    }
    float ps[4], pd[4];
    #pragma unroll
    for (int r = 0; r < 4; ++r) {
        float s = 0.f, d = 0.f;
        #pragma unroll
        for (int j = 0; j < 8; ++j) { s += acc[r][j] * asv[j]; d += acc[r][j] * adv[j]; }
        ps[r] = s; pd[r] = d;
    }
    #pragma unroll
    for (int sh = 1; sh < 8; sh <<= 1) {
        #pragma unroll
        for (int r = 0; r < 4; ++r) { ps[r] += __shfl_xor(ps[r], sh); pd[r] += __shfl_xor(pd[r], sh); }
    }
    int head = tcol >> 3;
    #pragma unroll
    for (int r = 0; r < 4; ++r) {
        int gr = r0 + trow * 4 + r;
        if (gr < nRows) {
            if ((tcol & 7) == 0) { a_s[gr * 2 + head] = ps[r]; a_d[gr * 2 + head] = pd[r]; }
            uint4 pk;
            pk.x = (unsigned)f2bf(acc[r][0]) | ((unsigned)f2bf(acc[r][1]) << 16);
            pk.y = (unsigned)f2bf(acc[r][2]) | ((unsigned)f2bf(acc[r][3]) << 16);
            pk.z = (unsigned)f2bf(acc[r][4]) | ((unsigned)f2bf(acc[r][5]) << 16);
            pk.w = (unsigned)f2bf(acc[r][6]) | ((unsigned)f2bf(acc[r][7]) << 16);
            *reinterpret_cast<uint4*>(&h1b[(size_t)gr * 128 + tcol * 8]) = pk;
        }
    }
}

// ---------------------------------------------------------------- GEMM2 fused (X2@W2 + att dots), bf16 h2 out
// thread: row trow=t>>2, contiguous cols tcol*10 .. tcol*10+9 (tcol=t&3)
__global__ __launch_bounds__(256) void gemm2_fused(const float* __restrict__ X, const float* __restrict__ W,
                                                   const float* __restrict__ asw, const float* __restrict__ adw,
                                                   unsigned short* __restrict__ h2b, float* __restrict__ a_s,
                                                   float* __restrict__ a_d, int nRows) {
    __shared__ float Ws[32][40];
    __shared__ float Xst[32][68];
    int t = threadIdx.x;
    int tcol = t & 3, trow = t >> 2;
    int r0 = blockIdx.x * 64;
    float acc[10];
    #pragma unroll
    for (int j = 0; j < 10; ++j) acc[j] = 0.f;
    float asv[10], adv[10];
    #pragma unroll
    for (int j = 0; j < 10; ++j) { asv[j] = asw[tcol * 10 + j]; adv[j] = adw[tcol * 10 + j]; }

    for (int kc = 0; kc < 4; ++kc) {
        int k0 = kc * 32;
        __syncthreads();
        for (int i = t; i < 32 * 40; i += 256) (&Ws[0][0])[i] = W[(size_t)k0 * 40 + i];
        #pragma unroll
        for (int i = 0; i < 2; ++i) {
            int li = t + i * 256;
            int r = li >> 3;
            int kk = (li & 7) * 4;
            int gr = r0 + r;
            float4 xv = make_float4(0.f, 0.f, 0.f, 0.f);
            if (gr < nRows) xv = *reinterpret_cast<const float4*>(&X[(size_t)gr * 128 + k0 + kk]);
            Xst[kk][r] = xv.x; Xst[kk + 1][r] = xv.y; Xst[kk + 2][r] = xv.z; Xst[kk + 3][r] = xv.w;
        }
        __syncthreads();
        #pragma unroll 8
        for (int k = 0; k < 32; ++k) {
            float xv = Xst[k][trow];
            #pragma unroll
            for (int j = 0; j < 10; ++j) acc[j] += xv * Ws[k][tcol * 10 + j];
        }
    }
    float ps = 0.f, pd = 0.f;
    #pragma unroll
    for (int j = 0; j < 10; ++j) { ps += acc[j] * asv[j]; pd += acc[j] * adv[j]; }
    ps += __shfl_xor(ps, 1); pd += __shfl_xor(pd, 1);
    ps += __shfl_xor(ps, 2); pd += __shfl_xor(pd, 2);
    int gr = r0 + trow;
    if (gr < nRows) {
        if (tcol == 0) { a_s[gr] = ps; a_d[gr] = pd; }
        unsigned int* dstp = reinterpret_cast<unsigned int*>(&h2b[(size_t)gr * 40 + tcol * 10]);
        #pragma unroll
        for (int jj = 0; jj < 5; ++jj)
            dstp[jj] = (unsigned)f2bf(acc[2 * jj]) | ((unsigned)f2bf(acc[2 * jj + 1]) << 16);
    }
}

// ---------------------------------------------------------------- aggregation layer1 (+bias+ELU)
// one wave per node; lane = (q=lane>>4, c=lane&15): edge-slot parity q, channels c*8..c*8+7 (bf16 uint4)
__global__ __launch_bounds__(256) void aggregate1(const unsigned short* __restrict__ Hb, const float* __restrict__ as,
                                                  const float* __restrict__ ad, const int* __restrict__ offs,
                                                  const int* __restrict__ ssrc, const float* __restrict__ bias,
                                                  float* __restrict__ Xout, int n) {
    __shared__ int   sbuf[4][64];
    __shared__ float wbuf[4][2][64];
    int t = threadIdx.x, lane = t & 63, wid = t >> 6;
    int node = blockIdx.x * 4 + wid;
    if (node >= n) return;
    int c = lane & 15, q = lane >> 4;
    int head = c >> 3;
    int beg = offs[node], end = offs[node + 1];
    float ad0 = ad[node * 2], ad1 = ad[node * 2 + 1];
    float den0 = 0.f, den1 = 0.f;
    float accA[8], accB[8];
    #pragma unroll
    for (int k = 0; k < 8; ++k) { accA[k] = 0.f; accB[k] = 0.f; }
    for (int i0 = beg; i0 < end; i0 += 64) {
        int cnt = min(64, end - i0);
        int s = 0; float w0 = 0.f, w1 = 0.f;
        if (lane < cnt) {
            s = ssrc[i0 + lane];
            w0 = __expf(lrelu(as[s * 2]     + ad0));
            w1 = __expf(lrelu(as[s * 2 + 1] + ad1));
        }
        sbuf[wid][lane]    = s;
        wbuf[wid][0][lane] = w0;
        wbuf[wid][1][lane] = w1;
        den0 += w0; den1 += w1;
        for (int j = 0; j < cnt; j += 8) {
            int ea = j + q, eb = j + 4 + q;
            int   sa = sbuf[wid][ea],       sb = sbuf[wid][eb];
            float wa = wbuf[wid][head][ea], wb = wbuf[wid][head][eb];
            uint4 ha = *reinterpret_cast<const uint4*>(&Hb[(size_t)sa * 128 + c * 8]);
            uint4 hb = *reinterpret_cast<const uint4*>(&Hb[(size_t)sb * 128 + c * 8]);
            accA[0] += wa * lo_bf(ha.x); accA[1] += wa * hi_bf(ha.x);
            accA[2] += wa * lo_bf(ha.y); accA[3] += wa * hi_bf(ha.y);
            accA[4] += wa * lo_bf(ha.z); accA[5] += wa * hi_bf(ha.z);
            accA[6] += wa * lo_bf(ha.w); accA[7] += wa * hi_bf(ha.w);
            accB[0] += wb * lo_bf(hb.x); accB[1] += wb * hi_bf(hb.x);
            accB[2] += wb * lo_bf(hb.y); accB[3] += wb * hi_bf(hb.y);
            accB[4] += wb * lo_bf(hb.z); accB[5] += wb * hi_bf(hb.z);
            accB[6] += wb * lo_bf(hb.w); accB[7] += wb * hi_bf(hb.w);
        }
    }
    #pragma unroll
    for (int k = 0; k < 8; ++k) accA[k] += accB[k];
    #pragma unroll
    for (int sh = 32; sh > 0; sh >>= 1) { den0 += __shfl_xor(den0, sh); den1 += __shfl_xor(den1, sh); }
    #pragma unroll
    for (int k = 0; k < 8; ++k) {
        accA[k] += __shfl_xor(accA[k], 16);
        accA[k] += __shfl_xor(accA[k], 32);
    }
    if (q == 0) {
        float den = (head ? den1 : den0) + 1e-16f;
        float4 b0 = *reinterpret_cast<const float4*>(&bias[c * 8]);
        float4 b1 = *reinterpret_cast<const float4*>(&bias[c * 8 + 4]);
        float bb[8] = {b0.x, b0.y, b0.z, b0.w, b1.x, b1.y, b1.z, b1.w};
        float o[8];
        #pragma unroll
        for (int k = 0; k < 8; ++k) {
            float v = accA[k] / den + bb[k];
            o[k] = v > 0.f ? v : (__expf(v) - 1.f);   // ELU
        }
        *reinterpret_cast<float4*>(&Xout[(size_t)node * 128 + c * 8])     = make_float4(o[0], o[1], o[2], o[3]);
        *reinterpret_cast<float4*>(&Xout[(size_t)node * 128 + c * 8 + 4]) = make_float4(o[4], o[5], o[6], o[7]);
    }
}

// ---------------------------------------------------------------- aggregation layer2 (+bias) -> out
// one wave per node; 6 edge-groups x 10 lanes, 4 bf16 ch/lane (uint2)
__global__ __launch_bounds__(256) void aggregate2(const unsigned short* __restrict__ Hb, const float* __restrict__ as,
                                                  const float* __restrict__ ad, const int* __restrict__ offs,
                                                  const int* __restrict__ ssrc, const float* __restrict__ bias,
                                                  float* __restrict__ out, int n) {
    __shared__ int   sbuf[4][80];
    __shared__ float wbuf[4][80];
    int t = threadIdx.x, lane = t & 63, wid = t >> 6;
    int node = blockIdx.x * 4 + wid;
    if (node >= n) return;
    int g = lane / 10, c4 = lane % 10;
    bool dead = (lane >= 60);
    if (dead) { c4 = lane - 60; }
    if (lane < 16) { sbuf[wid][64 + lane] = 0; wbuf[wid][64 + lane] = 0.f; }
    int beg = offs[node], end = offs[node + 1];
    float adv = ad[node];
    float den = 0.f;
    float accA[4] = {0.f, 0.f, 0.f, 0.f}, accB[4] = {0.f, 0.f, 0.f, 0.f};
    for (int i0 = beg; i0 < end; i0 += 64) {
        int cnt = min(64, end - i0);
        int s = 0; float w = 0.f;
        if (lane < cnt) {
            s = ssrc[i0 + lane];
            w = __expf(lrelu(as[s] + adv));
        }
        sbuf[wid][lane] = s;
        wbuf[wid][lane] = w;
        den += w;
        for (int j = 0; j < cnt; j += 12) {
            int ea = dead ? 72 : (j + g);
            int eb = dead ? 72 : (j + 6 + g);
            int   sa = sbuf[wid][ea], sb = sbuf[wid][eb];
            float wa = wbuf[wid][ea], wb = wbuf[wid][eb];
            uint2 ha = *reinterpret_cast<const uint2*>(&Hb[(size_t)sa * 40 + c4 * 4]);
            uint2 hb = *reinterpret_cast<const uint2*>(&Hb[(size_t)sb * 40 + c4 * 4]);
            accA[0] += wa * lo_bf(ha.x); accA[1] += wa * hi_bf(ha.x);
            accA[2] += wa * lo_bf(ha.y); accA[3] += wa * hi_bf(ha.y);
            accB[0] += wb * lo_bf(hb.x); accB[1] += wb * hi_bf(hb.x);
            accB[2] += wb * lo_bf(hb.y); accB[3] += wb * hi_bf(hb.y);
        }
    }
    #pragma unroll
    for (int k = 0; k < 4; ++k) accA[k] += accB[k];
    #pragma unroll
    for (int sh = 32; sh > 0; sh >>= 1) den += __shfl_xor(den, sh);
    // merge 6 groups: lane l<30 += lane l+30 ; then lanes <10 add l+10, l+20
    #pragma unroll
    for (int k = 0; k < 4; ++k) {
        float a = accA[k];
        float a30 = __shfl(a, lane + 30);
        a += a30;
        float a10 = __shfl(a, lane + 10);
        float a20 = __shfl(a, lane + 20);
        accA[k] = a + a10 + a20;
    }
    if (lane < 10) {
        float dinv = 1.f / (den + 1e-16f);
        float4 o;
        o.x = accA[0] * dinv + bias[c4 * 4];
        o.y = accA[1] * dinv + bias[c4 * 4 + 1];
        o.z = accA[2] * dinv + bias[c4 * 4 + 2];
        o.w = accA[3] * dinv + bias[c4 * 4 + 3];
        *reinterpret_cast<float4*>(&out[(size_t)node * 40 + c4 * 4]) = o;
    }
}

// ---------------------------------------------------------------- launch
extern "C" void kernel_launch(void* const* d_in, const int* in_sizes, int n_in,
                              void* d_out, int out_size, void* d_ws, size_t ws_size,
                              hipStream_t stream) {
    (void)in_sizes; (void)n_in; (void)out_size; (void)ws_size;
    const float* x    = (const float*)d_in[0];
    const int*   ei   = (const int*)d_in[1];
    const float* W1   = (const float*)d_in[2];
    const float* as1w = (const float*)d_in[3];
    const float* ad1w = (const float*)d_in[4];
    const float* b1   = (const float*)d_in[5];
    const float* W2   = (const float*)d_in[6];
    const float* as2w = (const float*)d_in[7];
    const float* ad2w = (const float*)d_in[8];
    const float* b2   = (const float*)d_in[9];
    float* out = (float*)d_out;

    float* ws = (float*)d_ws;
    float* h1slot = ws; ws += (size_t)N_NODES * 128;     // bf16 h1 uses half of this
    float* x2     = ws; ws += (size_t)N_NODES * 128;     // also aliased as rank[] before aggregate1
    float* a_s1 = ws; ws += N_NODES * 2;
    float* a_d1 = ws; ws += N_NODES * 2;
    float* a_s2 = ws; ws += N_NODES;
    float* a_d2 = ws; ws += N_NODES;
    float* h2slot = ws; ws += (size_t)N_NODES * 40;      // bf16 h2 uses part
    int* offs = (int*)ws;
    int* deg  = offs + 50004;
    int* ssrc = deg + N_NODES;

    unsigned short* h1b = (unsigned short*)h1slot;
    unsigned short* h2b = (unsigned short*)h2slot;
    int* rank = (int*)x2;    // dead after scatter_edges; x2 written later by aggregate1

    hipMemsetAsync(deg, 0, N_NODES * sizeof(int), stream);
    count_deg<<<(E_TOT + 255) / 256, 256, 0, stream>>>(ei, deg, rank);
    scan_kernel<<<1, 1024, 0, stream>>>(deg, offs, N_NODES);
    scatter_edges<<<(E_TOT + 255) / 256, 256, 0, stream>>>(ei, offs, rank, ssrc);

    gemm1_fused<<<(N_NODES + 63) / 64, 256, 0, stream>>>(x, W1, as1w, ad1w, h1b, a_s1, a_d1, N_NODES);
    aggregate1<<<(N_NODES + 3) / 4, 256, 0, stream>>>(h1b, a_s1, a_d1, offs, ssrc, b1, x2, N_NODES);
    gemm2_fused<<<(N_NODES + 63) / 64, 256, 0, stream>>>(x2, W2, as2w, ad2w, h2b, a_s2, a_d2, N_NODES);
    aggregate2<<<(N_NODES + 3) / 4, 256, 0, stream>>>(h2b, a_s2, a_d2, offs, ssrc, b2, out, N_NODES);
}

// Round 5
// 190.453 us; speedup vs baseline: 2.5863x; 1.0486x over previous
//
#include <hip/hip_runtime.h>
#include <hip/hip_bf16.h>

#define N_NODES 50000
#define E0      800000
#define E_TOT   850000   // +N self loops

typedef short short8 __attribute__((ext_vector_type(8)));
typedef float floatx4 __attribute__((ext_vector_type(4)));

__device__ __forceinline__ float lrelu(float x) { return x > 0.f ? x : 0.2f * x; }

__device__ __forceinline__ unsigned short f2bf(float f) {   // RNE fp32->bf16
    unsigned int u = __float_as_uint(f);
    u += 0x7fffu + ((u >> 16) & 1u);
    return (unsigned short)(u >> 16);
}
__device__ __forceinline__ float lo_bf(unsigned int p) { return __uint_as_float(p << 16); }
__device__ __forceinline__ float hi_bf(unsigned int p) { return __uint_as_float(p & 0xffff0000u); }

// ---------------------------------------------------------------- CSR build
__global__ __launch_bounds__(256) void zero_deg(int* __restrict__ deg) {
    int i = blockIdx.x * 256 + threadIdx.x;
    if (i < N_NODES) deg[i] = 0;
}

__global__ __launch_bounds__(256) void count_deg(const int* __restrict__ ei, int* __restrict__ deg,
                                                 int* __restrict__ rank) {
    int e = blockIdx.x * 256 + threadIdx.x;
    if (e >= E_TOT) return;
    int dst = (e < E0) ? ei[E0 + e] : (e - E0);
    rank[e] = atomicAdd(&deg[dst], 1);
}

__global__ __launch_bounds__(1024) void scan_kernel(const int* __restrict__ deg, int* __restrict__ offs, int n) {
    __shared__ int wsum[16];
    __shared__ int carry_sh;
    int t = threadIdx.x, lane = t & 63, wid = t >> 6;
    if (t == 0) carry_sh = 0;
    __syncthreads();
    for (int base = 0; base < n; base += 4096) {
        int idx = base + t * 4;
        int4 v = make_int4(0, 0, 0, 0);
        if (idx < n) v = *reinterpret_cast<const int4*>(deg + idx);
        int tsum = v.x + v.y + v.z + v.w;
        int sc = tsum;
        #pragma unroll
        for (int s = 1; s < 64; s <<= 1) {
            int up = __shfl_up(sc, s);
            if (lane >= s) sc += up;
        }
        if (lane == 63) wsum[wid] = sc;
        __syncthreads();
        int carry = carry_sh;
        int woff = 0;
        for (int w = 0; w < wid; ++w) woff += wsum[w];
        int b0 = carry + woff + (sc - tsum);
        if (idx < n) {
            int4 o;
            o.x = b0;
            o.y = b0 + v.x;
            o.z = b0 + v.x + v.y;
            o.w = b0 + v.x + v.y + v.z;
            *reinterpret_cast<int4*>(offs + idx) = o;
        }
        __syncthreads();
        if (t == 0) {
            int tt = 0;
            #pragma unroll
            for (int w = 0; w < 16; ++w) tt += wsum[w];
            carry_sh = carry + tt;
        }
        __syncthreads();
    }
    if (t == 0) offs[n] = carry_sh;
}

__global__ __launch_bounds__(256) void scatter_edges(const int* __restrict__ ei, const int* __restrict__ offs,
                                                     const int* __restrict__ rank, int* __restrict__ ssrc) {
    int e = blockIdx.x * 256 + threadIdx.x;
    if (e >= E_TOT) return;
    int src, dst;
    if (e < E0) { src = ei[e]; dst = ei[E0 + e]; }
    else        { src = dst = e - E0; }
    ssrc[offs[dst] + rank[e]] = src;
}

// ---------------------------------------------------------------- GEMM1 via MFMA bf16 (X@W1 + att dots)
// block: 256 thr = 4 waves; tile 64 rows x 128 cols, K=128.
// LDS: Xs [64 rows][128 k] bf16 (XOR-swizzled), Wt [128 n][128 k] bf16 transposed (XOR-swizzled)
__global__ __launch_bounds__(256) void gemm1_mfma(const float* __restrict__ X, const float* __restrict__ W,
                                                  const float* __restrict__ asw, const float* __restrict__ adw,
                                                  unsigned short* __restrict__ h1b, float* __restrict__ a_s,
                                                  float* __restrict__ a_d, int nRows) {
    __shared__ unsigned short Xs[64 * 128];
    __shared__ unsigned short Wt[128 * 128];
    int t = threadIdx.x, lane = t & 63, wave = t >> 6;
    int r0 = blockIdx.x * 64;
    char* XsB = (char*)Xs;
    char* WtB = (char*)Wt;

    // stage W transposed+swizzled: 4096 float4 units
    for (int i = t; i < 4096; i += 256) {
        int k = i >> 5, n4 = (i & 31) * 4;
        float4 w4 = *reinterpret_cast<const float4*>(&W[(size_t)k * 128 + n4]);
        const float* wf = reinterpret_cast<const float*>(&w4);
        #pragma unroll
        for (int j = 0; j < 4; ++j) {
            int nn = n4 + j;
            *reinterpret_cast<unsigned short*>(WtB + nn * 256 + ((k * 2) ^ ((nn & 7) << 4))) = f2bf(wf[j]);
        }
    }
    // stage X bf16 swizzled: 2048 float4 units (64 rows x 32 float4)
    for (int i = t; i < 2048; i += 256) {
        int r = i >> 5, k4 = (i & 31) * 4;
        int gr = r0 + r;
        float4 xv = make_float4(0.f, 0.f, 0.f, 0.f);
        if (gr < nRows) xv = *reinterpret_cast<const float4*>(&X[(size_t)gr * 128 + k4]);
        unsigned int p0 = (unsigned)f2bf(xv.x) | ((unsigned)f2bf(xv.y) << 16);
        unsigned int p1 = (unsigned)f2bf(xv.z) | ((unsigned)f2bf(xv.w) << 16);
        *reinterpret_cast<uint2*>(XsB + r * 256 + ((k4 * 2) ^ ((r & 7) << 4))) = make_uint2(p0, p1);
    }
    __syncthreads();

    int l15 = lane & 15, g = lane >> 4;
    float asv[8], adv[8];
    #pragma unroll
    for (int nt = 0; nt < 8; ++nt) { asv[nt] = asw[nt * 16 + l15]; adv[nt] = adw[nt * 16 + l15]; }

    floatx4 acc[8];
    #pragma unroll
    for (int nt = 0; nt < 8; ++nt) acc[nt] = (floatx4){0.f, 0.f, 0.f, 0.f};

    #pragma unroll
    for (int ks = 0; ks < 4; ++ks) {
        short8 afrag = *reinterpret_cast<short8*>(
            XsB + (wave * 16 + l15) * 256 + ((ks * 64 + g * 16) ^ ((l15 & 7) << 4)));
        #pragma unroll
        for (int nt = 0; nt < 8; ++nt) {
            int nn = nt * 16 + l15;
            short8 bfrag = *reinterpret_cast<short8*>(
                WtB + nn * 256 + ((ks * 64 + g * 16) ^ ((nn & 7) << 4)));
            acc[nt] = __builtin_amdgcn_mfma_f32_16x16x32_bf16(afrag, bfrag, acc[nt], 0, 0, 0);
        }
    }

    // epilogue: D[row=g*4+i][col=nt*16+l15]; rows gr = r0 + wave*16 + g*4 + i
    #pragma unroll
    for (int i = 0; i < 4; ++i) {
        int gr = r0 + wave * 16 + g * 4 + i;
        float s0 = 0.f, d0 = 0.f, s1 = 0.f, d1 = 0.f;
        #pragma unroll
        for (int nt = 0; nt < 4; ++nt) { s0 += acc[nt][i] * asv[nt]; d0 += acc[nt][i] * adv[nt]; }
        #pragma unroll
        for (int nt = 4; nt < 8; ++nt) { s1 += acc[nt][i] * asv[nt]; d1 += acc[nt][i] * adv[nt]; }
        #pragma unroll
        for (int sh = 1; sh < 16; sh <<= 1) {
            s0 += __shfl_xor(s0, sh); d0 += __shfl_xor(d0, sh);
            s1 += __shfl_xor(s1, sh); d1 += __shfl_xor(d1, sh);
        }
        if (gr < nRows) {
            if (l15 == 0) {
                a_s[gr * 2] = s0;     a_d[gr * 2] = d0;
                a_s[gr * 2 + 1] = s1; a_d[gr * 2 + 1] = d1;
            }
            #pragma unroll
            for (int nt = 0; nt < 8; ++nt)
                h1b[(size_t)gr * 128 + nt * 16 + l15] = f2bf(acc[nt][i]);
        }
    }
}

// ---------------------------------------------------------------- GEMM2 fused (X2@W2 + att dots), bf16 h2 out
__global__ __launch_bounds__(256) void gemm2_fused(const float* __restrict__ X, const float* __restrict__ W,
                                                   const float* __restrict__ asw, const float* __restrict__ adw,
                                                   unsigned short* __restrict__ h2b, float* __restrict__ a_s,
                                                   float* __restrict__ a_d, int nRows) {
    __shared__ float Ws[32][40];
    __shared__ float Xst[32][68];
    int t = threadIdx.x;
    int tcol = t & 3, trow = t >> 2;
    int r0 = blockIdx.x * 64;
    float acc[10];
    #pragma unroll
    for (int j = 0; j < 10; ++j) acc[j] = 0.f;
    float asv[10], adv[10];
    #pragma unroll
    for (int j = 0; j < 10; ++j) { asv[j] = asw[tcol * 10 + j]; adv[j] = adw[tcol * 10 + j]; }

    for (int kc = 0; kc < 4; ++kc) {
        int k0 = kc * 32;
        __syncthreads();
        for (int i = t; i < 32 * 40; i += 256) (&Ws[0][0])[i] = W[(size_t)k0 * 40 + i];
        #pragma unroll
        for (int i = 0; i < 2; ++i) {
            int li = t + i * 256;
            int r = li >> 3;
            int kk = (li & 7) * 4;
            int gr = r0 + r;
            float4 xv = make_float4(0.f, 0.f, 0.f, 0.f);
            if (gr < nRows) xv = *reinterpret_cast<const float4*>(&X[(size_t)gr * 128 + k0 + kk]);
            Xst[kk][r] = xv.x; Xst[kk + 1][r] = xv.y; Xst[kk + 2][r] = xv.z; Xst[kk + 3][r] = xv.w;
        }
        __syncthreads();
        #pragma unroll 8
        for (int k = 0; k < 32; ++k) {
            float xv = Xst[k][trow];
            #pragma unroll
            for (int j = 0; j < 10; ++j) acc[j] += xv * Ws[k][tcol * 10 + j];
        }
    }
    float ps = 0.f, pd = 0.f;
    #pragma unroll
    for (int j = 0; j < 10; ++j) { ps += acc[j] * asv[j]; pd += acc[j] * adv[j]; }
    ps += __shfl_xor(ps, 1); pd += __shfl_xor(pd, 1);
    ps += __shfl_xor(ps, 2); pd += __shfl_xor(pd, 2);
    int gr = r0 + trow;
    if (gr < nRows) {
        if (tcol == 0) { a_s[gr] = ps; a_d[gr] = pd; }
        unsigned int* dstp = reinterpret_cast<unsigned int*>(&h2b[(size_t)gr * 40 + tcol * 10]);
        #pragma unroll
        for (int jj = 0; jj < 5; ++jj)
            dstp[jj] = (unsigned)f2bf(acc[2 * jj]) | ((unsigned)f2bf(acc[2 * jj + 1]) << 16);
    }
}

// ---------------------------------------------------------------- aggregation layer1 (+bias+ELU)
__global__ __launch_bounds__(256) void aggregate1(const unsigned short* __restrict__ Hb, const float* __restrict__ as,
                                                  const float* __restrict__ ad, const int* __restrict__ offs,
                                                  const int* __restrict__ ssrc, const float* __restrict__ bias,
                                                  float* __restrict__ Xout, int n) {
    __shared__ int   sbuf[4][64];
    __shared__ float wbuf[4][2][64];
    int t = threadIdx.x, lane = t & 63, wid = t >> 6;
    int node = blockIdx.x * 4 + wid;
    if (node >= n) return;
    int c = lane & 15, q = lane >> 4;
    int head = c >> 3;
    int beg = offs[node], end = offs[node + 1];
    float ad0 = ad[node * 2], ad1 = ad[node * 2 + 1];
    float den0 = 0.f, den1 = 0.f;
    float accA[8], accB[8];
    #pragma unroll
    for (int k = 0; k < 8; ++k) { accA[k] = 0.f; accB[k] = 0.f; }
    for (int i0 = beg; i0 < end; i0 += 64) {
        int cnt = min(64, end - i0);
        int s = 0; float w0 = 0.f, w1 = 0.f;
        if (lane < cnt) {
            s = ssrc[i0 + lane];
            w0 = __expf(lrelu(as[s * 2]     + ad0));
            w1 = __expf(lrelu(as[s * 2 + 1] + ad1));
        }
        sbuf[wid][lane]    = s;
        wbuf[wid][0][lane] = w0;
        wbuf[wid][1][lane] = w1;
        den0 += w0; den1 += w1;
        for (int j = 0; j < cnt; j += 8) {
            int ea = j + q, eb = j + 4 + q;
            int   sa = sbuf[wid][ea],       sb = sbuf[wid][eb];
            float wa = wbuf[wid][head][ea], wb = wbuf[wid][head][eb];
            uint4 ha = *reinterpret_cast<const uint4*>(&Hb[(size_t)sa * 128 + c * 8]);
            uint4 hb = *reinterpret_cast<const uint4*>(&Hb[(size_t)sb * 128 + c * 8]);
            accA[0] += wa * lo_bf(ha.x); accA[1] += wa * hi_bf(ha.x);
            accA[2] += wa * lo_bf(ha.y); accA[3] += wa * hi_bf(ha.y);
            accA[4] += wa * lo_bf(ha.z); accA[5] += wa * hi_bf(ha.z);
            accA[6] += wa * lo_bf(ha.w); accA[7] += wa * hi_bf(ha.w);
            accB[0] += wb * lo_bf(hb.x); accB[1] += wb * hi_bf(hb.x);
            accB[2] += wb * lo_bf(hb.y); accB[3] += wb * hi_bf(hb.y);
            accB[4] += wb * lo_bf(hb.z); accB[5] += wb * hi_bf(hb.z);
            accB[6] += wb * lo_bf(hb.w); accB[7] += wb * hi_bf(hb.w);
        }
    }
    #pragma unroll
    for (int k = 0; k < 8; ++k) accA[k] += accB[k];
    #pragma unroll
    for (int sh = 32; sh > 0; sh >>= 1) { den0 += __shfl_xor(den0, sh); den1 += __shfl_xor(den1, sh); }
    #pragma unroll
    for (int k = 0; k < 8; ++k) {
        accA[k] += __shfl_xor(accA[k], 16);
        accA[k] += __shfl_xor(accA[k], 32);
    }
    if (q == 0) {
        float den = (head ? den1 : den0) + 1e-16f;
        float4 b0 = *reinterpret_cast<const float4*>(&bias[c * 8]);
        float4 b1 = *reinterpret_cast<const float4*>(&bias[c * 8 + 4]);
        float bb[8] = {b0.x, b0.y, b0.z, b0.w, b1.x, b1.y, b1.z, b1.w};
        float o[8];
        #pragma unroll
        for (int k = 0; k < 8; ++k) {
            float v = accA[k] / den + bb[k];
            o[k] = v > 0.f ? v : (__expf(v) - 1.f);   // ELU
        }
        *reinterpret_cast<float4*>(&Xout[(size_t)node * 128 + c * 8])     = make_float4(o[0], o[1], o[2], o[3]);
        *reinterpret_cast<float4*>(&Xout[(size_t)node * 128 + c * 8 + 4]) = make_float4(o[4], o[5], o[6], o[7]);
    }
}

// ---------------------------------------------------------------- aggregation layer2 (+bias) -> out
__global__ __launch_bounds__(256) void aggregate2(const unsigned short* __restrict__ Hb, const float* __restrict__ as,
                                                  const float* __restrict__ ad, const int* __restrict__ offs,
                                                  const int* __restrict__ ssrc, const float* __restrict__ bias,
                                                  float* __restrict__ out, int n) {
    __shared__ int   sbuf[4][80];
    __shared__ float wbuf[4][80];
    int t = threadIdx.x, lane = t & 63, wid = t >> 6;
    int node = blockIdx.x * 4 + wid;
    if (node >= n) return;
    int g = lane / 10, c4 = lane % 10;
    bool dead = (lane >= 60);
    if (dead) { c4 = lane - 60; }
    if (lane < 16) { sbuf[wid][64 + lane] = 0; wbuf[wid][64 + lane] = 0.f; }
    int beg = offs[node], end = offs[node + 1];
    float adv = ad[node];
    float den = 0.f;
    float accA[4] = {0.f, 0.f, 0.f, 0.f}, accB[4] = {0.f, 0.f, 0.f, 0.f};
    for (int i0 = beg; i0 < end; i0 += 64) {
        int cnt = min(64, end - i0);
        int s = 0; float w = 0.f;
        if (lane < cnt) {
            s = ssrc[i0 + lane];
            w = __expf(lrelu(as[s] + adv));
        }
        sbuf[wid][lane] = s;
        wbuf[wid][lane] = w;
        den += w;
        for (int j = 0; j < cnt; j += 12) {
            int ea = dead ? 72 : (j + g);
            int eb = dead ? 72 : (j + 6 + g);
            int   sa = sbuf[wid][ea], sb = sbuf[wid][eb];
            float wa = wbuf[wid][ea], wb = wbuf[wid][eb];
            uint2 ha = *reinterpret_cast<const uint2*>(&Hb[(size_t)sa * 40 + c4 * 4]);
            uint2 hb = *reinterpret_cast<const uint2*>(&Hb[(size_t)sb * 40 + c4 * 4]);
            accA[0] += wa * lo_bf(ha.x); accA[1] += wa * hi_bf(ha.x);
            accA[2] += wa * lo_bf(ha.y); accA[3] += wa * hi_bf(ha.y);
            accB[0] += wb * lo_bf(hb.x); accB[1] += wb * hi_bf(hb.x);
            accB[2] += wb * lo_bf(hb.y); accB[3] += wb * hi_bf(hb.y);
        }
    }
    #pragma unroll
    for (int k = 0; k < 4; ++k) accA[k] += accB[k];
    #pragma unroll
    for (int sh = 32; sh > 0; sh >>= 1) den += __shfl_xor(den, sh);
    #pragma unroll
    for (int k = 0; k < 4; ++k) {
        float a = accA[k];
        float a30 = __shfl(a, lane + 30);
        a += a30;
        float a10 = __shfl(a, lane + 10);
        float a20 = __shfl(a, lane + 20);
        accA[k] = a + a10 + a20;
    }
    if (lane < 10) {
        float dinv = 1.f / (den + 1e-16f);
        float4 o;
        o.x = accA[0] * dinv + bias[c4 * 4];
        o.y = accA[1] * dinv + bias[c4 * 4 + 1];
        o.z = accA[2] * dinv + bias[c4 * 4 + 2];
        o.w = accA[3] * dinv + bias[c4 * 4 + 3];
        *reinterpret_cast<float4*>(&out[(size_t)node * 40 + c4 * 4]) = o;
    }
}

// ---------------------------------------------------------------- launch
extern "C" void kernel_launch(void* const* d_in, const int* in_sizes, int n_in,
                              void* d_out, int out_size, void* d_ws, size_t ws_size,
                              hipStream_t stream) {
    (void)in_sizes; (void)n_in; (void)out_size; (void)ws_size;
    const float* x    = (const float*)d_in[0];
    const int*   ei   = (const int*)d_in[1];
    const float* W1   = (const float*)d_in[2];
    const float* as1w = (const float*)d_in[3];
    const float* ad1w = (const float*)d_in[4];
    const float* b1   = (const float*)d_in[5];
    const float* W2   = (const float*)d_in[6];
    const float* as2w = (const float*)d_in[7];
    const float* ad2w = (const float*)d_in[8];
    const float* b2   = (const float*)d_in[9];
    float* out = (float*)d_out;

    float* ws = (float*)d_ws;
    float* h1slot = ws; ws += (size_t)N_NODES * 128;
    float* x2     = ws; ws += (size_t)N_NODES * 128;
    float* a_s1 = ws; ws += N_NODES * 2;
    float* a_d1 = ws; ws += N_NODES * 2;
    float* a_s2 = ws; ws += N_NODES;
    float* a_d2 = ws; ws += N_NODES;
    float* h2slot = ws; ws += (size_t)N_NODES * 40;
    int* offs = (int*)ws;
    int* deg  = offs + 50004;
    int* ssrc = deg + N_NODES;

    unsigned short* h1b = (unsigned short*)h1slot;
    unsigned short* h2b = (unsigned short*)h2slot;
    int* rank = (int*)x2;    // dead after scatter_edges; x2 written later by aggregate1

    zero_deg<<<(N_NODES + 255) / 256, 256, 0, stream>>>(deg);
    count_deg<<<(E_TOT + 255) / 256, 256, 0, stream>>>(ei, deg, rank);
    scan_kernel<<<1, 1024, 0, stream>>>(deg, offs, N_NODES);
    scatter_edges<<<(E_TOT + 255) / 256, 256, 0, stream>>>(ei, offs, rank, ssrc);

    gemm1_mfma<<<(N_NODES + 63) / 64, 256, 0, stream>>>(x, W1, as1w, ad1w, h1b, a_s1, a_d1, N_NODES);
    aggregate1<<<(N_NODES + 3) / 4, 256, 0, stream>>>(h1b, a_s1, a_d1, offs, ssrc, b1, x2, N_NODES);
    gemm2_fused<<<(N_NODES + 63) / 64, 256, 0, stream>>>(x2, W2, as2w, ad2w, h2b, a_s2, a_d2, N_NODES);
    aggregate2<<<(N_NODES + 3) / 4, 256, 0, stream>>>(h2b, a_s2, a_d2, offs, ssrc, b2, out, N_NODES);
}

// Round 6
// 166.621 us; speedup vs baseline: 2.9562x; 1.1430x over previous
//
#include <hip/hip_runtime.h>
#include <hip/hip_bf16.h>

#define N_NODES 50000
#define E0      800000
#define E_TOT   850000   // +N self loops

typedef short short8 __attribute__((ext_vector_type(8)));
typedef float floatx4 __attribute__((ext_vector_type(4)));

__device__ __forceinline__ float lrelu(float x) { return x > 0.f ? x : 0.2f * x; }

__device__ __forceinline__ unsigned short f2bf(float f) {   // RNE fp32->bf16
    unsigned int u = __float_as_uint(f);
    u += 0x7fffu + ((u >> 16) & 1u);
    return (unsigned short)(u >> 16);
}
__device__ __forceinline__ float lo_bf(unsigned int p) { return __uint_as_float(p << 16); }
__device__ __forceinline__ float hi_bf(unsigned int p) { return __uint_as_float(p & 0xffff0000u); }

__device__ __forceinline__ short8 pack_bf16x8(float4 a, float4 b) {
    short8 r;
    r[0] = (short)f2bf(a.x); r[1] = (short)f2bf(a.y); r[2] = (short)f2bf(a.z); r[3] = (short)f2bf(a.w);
    r[4] = (short)f2bf(b.x); r[5] = (short)f2bf(b.y); r[6] = (short)f2bf(b.z); r[7] = (short)f2bf(b.w);
    return r;
}

// ---------------------------------------------------------------- weight prep (once)
__global__ __launch_bounds__(256) void prep_w(const float* __restrict__ W1, const float* __restrict__ W2,
                                              unsigned short* __restrict__ Wt1, unsigned short* __restrict__ Wt2) {
    int i = blockIdx.x * 256 + threadIdx.x;
    if (i < 128 * 128) {
        int nn = i >> 7, k = i & 127;
        Wt1[i] = f2bf(W1[k * 128 + nn]);
    } else if (i < 128 * 128 + 48 * 128) {
        int j = i - 128 * 128;
        int nn = j >> 7, k = j & 127;
        Wt2[j] = (nn < 40) ? f2bf(W2[k * 40 + nn]) : (unsigned short)0;
    }
}

// ---------------------------------------------------------------- CSR build
__global__ __launch_bounds__(256) void zero_deg(int* __restrict__ deg) {
    int i = blockIdx.x * 256 + threadIdx.x;
    if (i < N_NODES) deg[i] = 0;
}

__global__ __launch_bounds__(256) void count_deg(const int* __restrict__ ei, int* __restrict__ deg,
                                                 int* __restrict__ rank) {
    int e = blockIdx.x * 256 + threadIdx.x;
    if (e >= E_TOT) return;
    int dst = (e < E0) ? ei[E0 + e] : (e - E0);
    rank[e] = atomicAdd(&deg[dst], 1);
}

// two-level scan: local (1024 ints/block) -> tops -> add
__global__ __launch_bounds__(256) void scan_local(const int* __restrict__ deg, int* __restrict__ offs,
                                                  int* __restrict__ bsum, int n) {
    __shared__ int wsum[4];
    int t = threadIdx.x, lane = t & 63, wid = t >> 6;
    int idx = blockIdx.x * 1024 + t * 4;
    int4 v = make_int4(0, 0, 0, 0);
    if (idx < n) v = *reinterpret_cast<const int4*>(deg + idx);
    int tsum = v.x + v.y + v.z + v.w;
    int sc = tsum;
    #pragma unroll
    for (int s = 1; s < 64; s <<= 1) {
        int up = __shfl_up(sc, s);
        if (lane >= s) sc += up;
    }
    if (lane == 63) wsum[wid] = sc;
    __syncthreads();
    int woff = 0;
    for (int w = 0; w < wid; ++w) woff += wsum[w];
    int b0 = woff + (sc - tsum);
    if (idx < n) {
        int4 o;
        o.x = b0;
        o.y = b0 + v.x;
        o.z = b0 + v.x + v.y;
        o.w = b0 + v.x + v.y + v.z;
        *reinterpret_cast<int4*>(offs + idx) = o;
    }
    if (t == 255) bsum[blockIdx.x] = woff + sc;
}

__global__ __launch_bounds__(64) void scan_tops(int* __restrict__ bsum, int* __restrict__ offs_n, int nb) {
    int lane = threadIdx.x;
    int v = (lane < nb) ? bsum[lane] : 0;
    int sc = v;
    #pragma unroll
    for (int s = 1; s < 64; s <<= 1) {
        int up = __shfl_up(sc, s);
        if (lane >= s) sc += up;
    }
    if (lane < nb) bsum[lane] = sc - v;      // exclusive
    int total = __shfl(sc, nb - 1);
    if (lane == 0) offs_n[0] = total;
}

__global__ __launch_bounds__(256) void scan_addoff(int* __restrict__ offs, const int* __restrict__ bsum, int n) {
    int idx = blockIdx.x * 1024 + threadIdx.x * 4;
    if (idx >= n) return;
    int add = bsum[blockIdx.x];
    int4 v = *reinterpret_cast<int4*>(offs + idx);
    v.x += add; v.y += add; v.z += add; v.w += add;
    *reinterpret_cast<int4*>(offs + idx) = v;
}

__global__ __launch_bounds__(256) void scatter_edges(const int* __restrict__ ei, const int* __restrict__ offs,
                                                     const int* __restrict__ rank, int* __restrict__ ssrc) {
    int e = blockIdx.x * 256 + threadIdx.x;
    if (e >= E_TOT) return;
    int src, dst;
    if (e < E0) { src = ei[e]; dst = ei[E0 + e]; }
    else        { src = dst = e - E0; }
    ssrc[offs[dst] + rank[e]] = src;
}

// ---------------------------------------------------------------- GEMM1 MFMA, LDS-free (X@W1 + att dots)
// block: 4 waves x 16 rows = 64 rows, 128 cols (8 nt tiles). A from X fp32 (in-reg bf16), B from Wt1 bf16.
__global__ __launch_bounds__(256) void gemm1_mfma(const float* __restrict__ X, const unsigned short* __restrict__ Wt,
                                                  const float* __restrict__ asw, const float* __restrict__ adw,
                                                  unsigned short* __restrict__ h1b, float* __restrict__ a_s,
                                                  float* __restrict__ a_d, int nRows) {
    int t = threadIdx.x, lane = t & 63, wave = t >> 6;
    int l15 = lane & 15, g = lane >> 4;
    int r0 = blockIdx.x * 64;
    int row = r0 + wave * 16 + l15;
    bool rv = row < nRows;
    const float* xrow = X + (size_t)(rv ? row : 0) * 128;

    float asv[8], adv[8];
    #pragma unroll
    for (int nt = 0; nt < 8; ++nt) { asv[nt] = asw[nt * 16 + l15]; adv[nt] = adw[nt * 16 + l15]; }

    floatx4 acc[8];
    #pragma unroll
    for (int nt = 0; nt < 8; ++nt) acc[nt] = (floatx4){0.f, 0.f, 0.f, 0.f};

    #pragma unroll
    for (int ks = 0; ks < 4; ++ks) {
        float4 xa = *reinterpret_cast<const float4*>(xrow + ks * 32 + g * 8);
        float4 xb = *reinterpret_cast<const float4*>(xrow + ks * 32 + g * 8 + 4);
        short8 af = pack_bf16x8(xa, xb);
        #pragma unroll
        for (int nt = 0; nt < 8; ++nt) {
            short8 bf = *reinterpret_cast<const short8*>(Wt + (size_t)(nt * 16 + l15) * 128 + ks * 32 + g * 8);
            acc[nt] = __builtin_amdgcn_mfma_f32_16x16x32_bf16(af, bf, acc[nt], 0, 0, 0);
        }
    }

    // epilogue: D[row=g*4+i][col=nt*16+l15]; rows gr = r0 + wave*16 + g*4 + i
    #pragma unroll
    for (int i = 0; i < 4; ++i) {
        int gr = r0 + wave * 16 + g * 4 + i;
        float s0 = 0.f, d0 = 0.f, s1 = 0.f, d1 = 0.f;
        #pragma unroll
        for (int nt = 0; nt < 4; ++nt) { s0 += acc[nt][i] * asv[nt]; d0 += acc[nt][i] * adv[nt]; }
        #pragma unroll
        for (int nt = 4; nt < 8; ++nt) { s1 += acc[nt][i] * asv[nt]; d1 += acc[nt][i] * adv[nt]; }
        #pragma unroll
        for (int sh = 1; sh < 16; sh <<= 1) {
            s0 += __shfl_xor(s0, sh); d0 += __shfl_xor(d0, sh);
            s1 += __shfl_xor(s1, sh); d1 += __shfl_xor(d1, sh);
        }
        if (gr < nRows) {
            if (l15 == 0) {
                a_s[gr * 2] = s0;     a_d[gr * 2] = d0;
                a_s[gr * 2 + 1] = s1; a_d[gr * 2 + 1] = d1;
            }
            #pragma unroll
            for (int nt = 0; nt < 8; ++nt)
                h1b[(size_t)gr * 128 + nt * 16 + l15] = f2bf(acc[nt][i]);
        }
    }
}

// ---------------------------------------------------------------- GEMM2 MFMA, LDS-free (X2@W2 + att dots), N=40 (pad 48)
__global__ __launch_bounds__(256) void gemm2_mfma(const float* __restrict__ X, const unsigned short* __restrict__ Wt,
                                                  const float* __restrict__ asw, const float* __restrict__ adw,
                                                  unsigned short* __restrict__ h2b, float* __restrict__ a_s,
                                                  float* __restrict__ a_d, int nRows) {
    int t = threadIdx.x, lane = t & 63, wave = t >> 6;
    int l15 = lane & 15, g = lane >> 4;
    int r0 = blockIdx.x * 64;
    int row = r0 + wave * 16 + l15;
    bool rv = row < nRows;
    const float* xrow = X + (size_t)(rv ? row : 0) * 128;

    float asv[3], adv[3];
    #pragma unroll
    for (int nt = 0; nt < 3; ++nt) {
        int col = nt * 16 + l15;
        asv[nt] = (col < 40) ? asw[col] : 0.f;
        adv[nt] = (col < 40) ? adw[col] : 0.f;
    }

    floatx4 acc[3];
    #pragma unroll
    for (int nt = 0; nt < 3; ++nt) acc[nt] = (floatx4){0.f, 0.f, 0.f, 0.f};

    #pragma unroll
    for (int ks = 0; ks < 4; ++ks) {
        float4 xa = *reinterpret_cast<const float4*>(xrow + ks * 32 + g * 8);
        float4 xb = *reinterpret_cast<const float4*>(xrow + ks * 32 + g * 8 + 4);
        short8 af = pack_bf16x8(xa, xb);
        #pragma unroll
        for (int nt = 0; nt < 3; ++nt) {
            short8 bf = *reinterpret_cast<const short8*>(Wt + (size_t)(nt * 16 + l15) * 128 + ks * 32 + g * 8);
            acc[nt] = __builtin_amdgcn_mfma_f32_16x16x32_bf16(af, bf, acc[nt], 0, 0, 0);
        }
    }

    #pragma unroll
    for (int i = 0; i < 4; ++i) {
        int gr = r0 + wave * 16 + g * 4 + i;
        float ps = 0.f, pd = 0.f;
        #pragma unroll
        for (int nt = 0; nt < 3; ++nt) { ps += acc[nt][i] * asv[nt]; pd += acc[nt][i] * adv[nt]; }
        #pragma unroll
        for (int sh = 1; sh < 16; sh <<= 1) { ps += __shfl_xor(ps, sh); pd += __shfl_xor(pd, sh); }
        if (gr < nRows) {
            if (l15 == 0) { a_s[gr] = ps; a_d[gr] = pd; }
            #pragma unroll
            for (int nt = 0; nt < 3; ++nt) {
                int col = nt * 16 + l15;
                if (col < 40) h2b[(size_t)gr * 40 + col] = f2bf(acc[nt][i]);
            }
        }
    }
}

// ---------------------------------------------------------------- aggregation layer1 (+bias+ELU), 4-deep gathers
__global__ __launch_bounds__(256) void aggregate1(const unsigned short* __restrict__ Hb, const float* __restrict__ as,
                                                  const float* __restrict__ ad, const int* __restrict__ offs,
                                                  const int* __restrict__ ssrc, const float* __restrict__ bias,
                                                  float* __restrict__ Xout, int n) {
    __shared__ int   sbuf[4][64];
    __shared__ float wbuf[4][2][64];
    int t = threadIdx.x, lane = t & 63, wid = t >> 6;
    int node = blockIdx.x * 4 + wid;
    if (node >= n) return;
    int c = lane & 15, q = lane >> 4;
    int head = c >> 3;
    int beg = offs[node], end = offs[node + 1];
    float ad0 = ad[node * 2], ad1 = ad[node * 2 + 1];
    float den0 = 0.f, den1 = 0.f;
    float accA[8], accB[8], accC[8], accD[8];
    #pragma unroll
    for (int k = 0; k < 8; ++k) { accA[k] = 0.f; accB[k] = 0.f; accC[k] = 0.f; accD[k] = 0.f; }
    for (int i0 = beg; i0 < end; i0 += 64) {
        int cnt = min(64, end - i0);
        int s = 0; float w0 = 0.f, w1 = 0.f;
        if (lane < cnt) {
            s = ssrc[i0 + lane];
            w0 = __expf(lrelu(as[s * 2]     + ad0));
            w1 = __expf(lrelu(as[s * 2 + 1] + ad1));
        }
        sbuf[wid][lane]    = s;
        wbuf[wid][0][lane] = w0;
        wbuf[wid][1][lane] = w1;
        den0 += w0; den1 += w1;
        for (int j = 0; j < cnt; j += 16) {
            int e0 = j + q, e1 = j + 4 + q, e2 = j + 8 + q, e3 = j + 12 + q;
            int   s0 = sbuf[wid][e0], s1 = sbuf[wid][e1], s2 = sbuf[wid][e2], s3 = sbuf[wid][e3];
            float wa = wbuf[wid][head][e0], wb = wbuf[wid][head][e1];
            float wc = wbuf[wid][head][e2], wd = wbuf[wid][head][e3];
            uint4 h0 = *reinterpret_cast<const uint4*>(&Hb[(size_t)s0 * 128 + c * 8]);
            uint4 h1 = *reinterpret_cast<const uint4*>(&Hb[(size_t)s1 * 128 + c * 8]);
            uint4 h2 = *reinterpret_cast<const uint4*>(&Hb[(size_t)s2 * 128 + c * 8]);
            uint4 h3 = *reinterpret_cast<const uint4*>(&Hb[(size_t)s3 * 128 + c * 8]);
            accA[0] += wa * lo_bf(h0.x); accA[1] += wa * hi_bf(h0.x);
            accA[2] += wa * lo_bf(h0.y); accA[3] += wa * hi_bf(h0.y);
            accA[4] += wa * lo_bf(h0.z); accA[5] += wa * hi_bf(h0.z);
            accA[6] += wa * lo_bf(h0.w); accA[7] += wa * hi_bf(h0.w);
            accB[0] += wb * lo_bf(h1.x); accB[1] += wb * hi_bf(h1.x);
            accB[2] += wb * lo_bf(h1.y); accB[3] += wb * hi_bf(h1.y);
            accB[4] += wb * lo_bf(h1.z); accB[5] += wb * hi_bf(h1.z);
            accB[6] += wb * lo_bf(h1.w); accB[7] += wb * hi_bf(h1.w);
            accC[0] += wc * lo_bf(h2.x); accC[1] += wc * hi_bf(h2.x);
            accC[2] += wc * lo_bf(h2.y); accC[3] += wc * hi_bf(h2.y);
            accC[4] += wc * lo_bf(h2.z); accC[5] += wc * hi_bf(h2.z);
            accC[6] += wc * lo_bf(h2.w); accC[7] += wc * hi_bf(h2.w);
            accD[0] += wd * lo_bf(h3.x); accD[1] += wd * hi_bf(h3.x);
            accD[2] += wd * lo_bf(h3.y); accD[3] += wd * hi_bf(h3.y);
            accD[4] += wd * lo_bf(h3.z); accD[5] += wd * hi_bf(h3.z);
            accD[6] += wd * lo_bf(h3.w); accD[7] += wd * hi_bf(h3.w);
        }
    }
    #pragma unroll
    for (int k = 0; k < 8; ++k) accA[k] += accB[k] + accC[k] + accD[k];
    #pragma unroll
    for (int sh = 32; sh > 0; sh >>= 1) { den0 += __shfl_xor(den0, sh); den1 += __shfl_xor(den1, sh); }
    #pragma unroll
    for (int k = 0; k < 8; ++k) {
        accA[k] += __shfl_xor(accA[k], 16);
        accA[k] += __shfl_xor(accA[k], 32);
    }
    if (q == 0) {
        float den = (head ? den1 : den0) + 1e-16f;
        float4 b0 = *reinterpret_cast<const float4*>(&bias[c * 8]);
        float4 b1 = *reinterpret_cast<const float4*>(&bias[c * 8 + 4]);
        float bb[8] = {b0.x, b0.y, b0.z, b0.w, b1.x, b1.y, b1.z, b1.w};
        float o[8];
        #pragma unroll
        for (int k = 0; k < 8; ++k) {
            float v = accA[k] / den + bb[k];
            o[k] = v > 0.f ? v : (__expf(v) - 1.f);   // ELU
        }
        *reinterpret_cast<float4*>(&Xout[(size_t)node * 128 + c * 8])     = make_float4(o[0], o[1], o[2], o[3]);
        *reinterpret_cast<float4*>(&Xout[(size_t)node * 128 + c * 8 + 4]) = make_float4(o[4], o[5], o[6], o[7]);
    }
}

// ---------------------------------------------------------------- aggregation layer2 (+bias) -> out, 4-deep gathers
__global__ __launch_bounds__(256) void aggregate2(const unsigned short* __restrict__ Hb, const float* __restrict__ as,
                                                  const float* __restrict__ ad, const int* __restrict__ offs,
                                                  const int* __restrict__ ssrc, const float* __restrict__ bias,
                                                  float* __restrict__ out, int n) {
    __shared__ int   sbuf[4][96];
    __shared__ float wbuf[4][96];
    int t = threadIdx.x, lane = t & 63, wid = t >> 6;
    int node = blockIdx.x * 4 + wid;
    if (node >= n) return;
    int g = lane / 10, c4 = lane % 10;
    bool dead = (lane >= 60);
    if (dead) c4 = lane - 60;
    if (lane < 32) { sbuf[wid][64 + lane] = 0; wbuf[wid][64 + lane] = 0.f; }
    int beg = offs[node], end = offs[node + 1];
    float adv = ad[node];
    float den = 0.f;
    float accA[4] = {0.f, 0.f, 0.f, 0.f}, accB[4] = {0.f, 0.f, 0.f, 0.f};
    float accC[4] = {0.f, 0.f, 0.f, 0.f}, accD[4] = {0.f, 0.f, 0.f, 0.f};
    for (int i0 = beg; i0 < end; i0 += 64) {
        int cnt = min(64, end - i0);
        int s = 0; float w = 0.f;
        if (lane < cnt) {
            s = ssrc[i0 + lane];
            w = __expf(lrelu(as[s] + adv));
        }
        sbuf[wid][lane] = s;
        wbuf[wid][lane] = w;
        den += w;
        for (int j = 0; j < cnt; j += 24) {
            int e0 = dead ? 88 : (j + g);
            int e1 = dead ? 88 : (j + 6 + g);
            int e2 = dead ? 88 : (j + 12 + g);
            int e3 = dead ? 88 : (j + 18 + g);
            int   s0 = sbuf[wid][e0], s1 = sbuf[wid][e1], s2 = sbuf[wid][e2], s3 = sbuf[wid][e3];
            float wa = wbuf[wid][e0], wb = wbuf[wid][e1], wc = wbuf[wid][e2], wd = wbuf[wid][e3];
            uint2 h0 = *reinterpret_cast<const uint2*>(&Hb[(size_t)s0 * 40 + c4 * 4]);
            uint2 h1 = *reinterpret_cast<const uint2*>(&Hb[(size_t)s1 * 40 + c4 * 4]);
            uint2 h2 = *reinterpret_cast<const uint2*>(&Hb[(size_t)s2 * 40 + c4 * 4]);
            uint2 h3 = *reinterpret_cast<const uint2*>(&Hb[(size_t)s3 * 40 + c4 * 4]);
            accA[0] += wa * lo_bf(h0.x); accA[1] += wa * hi_bf(h0.x);
            accA[2] += wa * lo_bf(h0.y); accA[3] += wa * hi_bf(h0.y);
            accB[0] += wb * lo_bf(h1.x); accB[1] += wb * hi_bf(h1.x);
            accB[2] += wb * lo_bf(h1.y); accB[3] += wb * hi_bf(h1.y);
            accC[0] += wc * lo_bf(h2.x); accC[1] += wc * hi_bf(h2.x);
            accC[2] += wc * lo_bf(h2.y); accC[3] += wc * hi_bf(h2.y);
            accD[0] += wd * lo_bf(h3.x); accD[1] += wd * hi_bf(h3.x);
            accD[2] += wd * lo_bf(h3.y); accD[3] += wd * hi_bf(h3.y);
        }
    }
    #pragma unroll
    for (int k = 0; k < 4; ++k) accA[k] += accB[k] + accC[k] + accD[k];
    #pragma unroll
    for (int sh = 32; sh > 0; sh >>= 1) den += __shfl_xor(den, sh);
    #pragma unroll
    for (int k = 0; k < 4; ++k) {
        float a = accA[k];
        float a30 = __shfl(a, lane + 30);
        a += a30;
        float a10 = __shfl(a, lane + 10);
        float a20 = __shfl(a, lane + 20);
        accA[k] = a + a10 + a20;
    }
    if (lane < 10) {
        float dinv = 1.f / (den + 1e-16f);
        float4 o;
        o.x = accA[0] * dinv + bias[c4 * 4];
        o.y = accA[1] * dinv + bias[c4 * 4 + 1];
        o.z = accA[2] * dinv + bias[c4 * 4 + 2];
        o.w = accA[3] * dinv + bias[c4 * 4 + 3];
        *reinterpret_cast<float4*>(&out[(size_t)node * 40 + c4 * 4]) = o;
    }
}

// ---------------------------------------------------------------- launch
extern "C" void kernel_launch(void* const* d_in, const int* in_sizes, int n_in,
                              void* d_out, int out_size, void* d_ws, size_t ws_size,
                              hipStream_t stream) {
    (void)in_sizes; (void)n_in; (void)out_size; (void)ws_size;
    const float* x    = (const float*)d_in[0];
    const int*   ei   = (const int*)d_in[1];
    const float* W1   = (const float*)d_in[2];
    const float* as1w = (const float*)d_in[3];
    const float* ad1w = (const float*)d_in[4];
    const float* b1   = (const float*)d_in[5];
    const float* W2   = (const float*)d_in[6];
    const float* as2w = (const float*)d_in[7];
    const float* ad2w = (const float*)d_in[8];
    const float* b2   = (const float*)d_in[9];
    float* out = (float*)d_out;

    float* ws = (float*)d_ws;
    float* h1slot = ws; ws += (size_t)N_NODES * 128;
    float* x2     = ws; ws += (size_t)N_NODES * 128;
    float* a_s1 = ws; ws += N_NODES * 2;
    float* a_d1 = ws; ws += N_NODES * 2;
    float* a_s2 = ws; ws += N_NODES;
    float* a_d2 = ws; ws += N_NODES;
    float* h2slot = ws; ws += (size_t)N_NODES * 40;
    int* offs = (int*)ws;
    int* deg  = offs + 50004;
    int* ssrc = deg + N_NODES;
    int* bsum = ssrc + E_TOT;                         // 64 ints
    unsigned short* Wt1 = (unsigned short*)(bsum + 64);
    unsigned short* Wt2 = Wt1 + 128 * 128;

    unsigned short* h1b = (unsigned short*)h1slot;
    unsigned short* h2b = (unsigned short*)h2slot;
    int* rank = (int*)x2;    // dead after scatter_edges; x2 written later by aggregate1

    const int NB = (N_NODES + 1023) / 1024;           // 49

    prep_w<<<88, 256, 0, stream>>>(W1, W2, Wt1, Wt2);
    zero_deg<<<(N_NODES + 255) / 256, 256, 0, stream>>>(deg);
    count_deg<<<(E_TOT + 255) / 256, 256, 0, stream>>>(ei, deg, rank);
    scan_local<<<NB, 256, 0, stream>>>(deg, offs, bsum, N_NODES);
    scan_tops<<<1, 64, 0, stream>>>(bsum, offs + N_NODES, NB);
    scan_addoff<<<NB, 256, 0, stream>>>(offs, bsum, N_NODES);
    scatter_edges<<<(E_TOT + 255) / 256, 256, 0, stream>>>(ei, offs, rank, ssrc);

    gemm1_mfma<<<(N_NODES + 63) / 64, 256, 0, stream>>>(x, Wt1, as1w, ad1w, h1b, a_s1, a_d1, N_NODES);
    aggregate1<<<(N_NODES + 3) / 4, 256, 0, stream>>>(h1b, a_s1, a_d1, offs, ssrc, b1, x2, N_NODES);
    gemm2_mfma<<<(N_NODES + 63) / 64, 256, 0, stream>>>(x2, Wt2, as2w, ad2w, h2b, a_s2, a_d2, N_NODES);
    aggregate2<<<(N_NODES + 3) / 4, 256, 0, stream>>>(h2b, a_s2, a_d2, offs, ssrc, b2, out, N_NODES);
}